// Round 3
// baseline (735.228 us; speedup 1.0000x reference)
//
#include <hip/hip_runtime.h>
#include <hip/hip_bf16.h>

// ---------------------------------------------------------------------------
// QuadraticGNN: 3x ResGatedGraphConv (ReLU gate, LeakyReLU 0.01, linear Wl)
//               -> global mean pool (32 graphs) -> 5-layer MLP with BN.
// Round 15:
//   - R14 gemm was structure-bound at ~326 TF (classic 2-barrier loop:
//     every K-step = stage -> barrier -> compute -> barrier, serializing a
//     full HBM round trip; MfmaUtil 11.5%, 2.2 TB/s). Now T14 async-split
//     + LDS double-buffer: issue t+1 global loads into regs at top of
//     iter t, compute t from buf[cur], ds_write regs -> buf[cur^1] after
//     compute, ONE barrier per K-step. LDS 26->52 KB (still 2 blocks/CU),
//     +12 VGPR staging regs (~75+32 < 128, occupancy unchanged).
//   - Everything else unchanged from R14 (QV-interleaved Gbf, 8-edge
//     batched gathers, striped pool atomics).
// ---------------------------------------------------------------------------

#define GN_N 100000
#define GN_E 300000
#define GN_G 32

typedef __attribute__((ext_vector_type(8))) short short8;
typedef __attribute__((ext_vector_type(4))) float floatx4;

__device__ inline ushort f2bf_rne(float f) {
    unsigned u = __float_as_uint(f);
    unsigned r = u + 0x7fffu + ((u >> 16) & 1u);
    return (ushort)(r >> 16);
}
__device__ inline float bf2f(ushort h) { return __uint_as_float(((unsigned)h) << 16); }

// W-array layout (ushort offsets), k-major [col][K] per segment.
#define WOFF_L2   32768
#define WOFF_L3   65536
#define WOFF_WL1  196608
#define WOFF_WL2  200704
#define W_TOTAL   217088

struct WSrc {
    const float* Wg[3][4];
    const float* Wl[2];
    const float* bg[3][4];
};

__global__ void wconv(WSrc S, ushort* __restrict__ hi, ushort* __restrict__ lo,
                      float* __restrict__ biascat)
{
    int id = blockIdx.x * 256 + threadIdx.x;
    if (id < 196608) {
        int l, base, ci, co;
        if (id < 32768)      { l = 0; base = 0;        ci = 128; co = 64;  }
        else if (id < 65536) { l = 1; base = WOFF_L2;  ci = 64;  co = 128; }
        else                 { l = 2; base = WOFF_L3;  ci = 128; co = 256; }
        int r  = id - base;
        int g  = r / (co * ci);
        int r2 = r - g * co * ci;
        int c  = r2 / ci;
        int k  = r2 - c * ci;
        float v = S.Wg[l][g][k * co + c];
        int ch  = c >> 6;
        int cc  = c & 63;
        // packed col within 256-chunk: K->cc, Q->64+2cc, V->65+2cc, S->192+cc
        int colIdx = (g == 0) ? cc : (g == 3) ? (192 + cc) : (64 + 2 * cc + (g - 1));
        int dst = base + ch * (256 * ci) + colIdx * ci + k;
        ushort h = f2bf_rne(v);
        hi[dst] = h; lo[dst] = f2bf_rne(v - bf2f(h));
    } else if (id < 196608 + 4096) {
        int r = id - 196608;
        int c = r >> 6, k = r & 63;
        float v = S.Wl[0][k * 64 + c];
        int dst = WOFF_WL1 + c * 64 + k;
        ushort h = f2bf_rne(v);
        hi[dst] = h; lo[dst] = f2bf_rne(v - bf2f(h));
    } else if (id < W_TOTAL) {
        int r = id - WOFF_WL2;
        int c = r >> 7, k2 = r & 127;
        float v = S.Wl[1][k2 * 128 + c];
        int dst = WOFF_WL2 + c * 128 + k2;
        ushort h = f2bf_rne(v);
        hi[dst] = h; lo[dst] = f2bf_rne(v - bf2f(h));
    } else if (id < W_TOTAL + 1792) {
        int i = id - W_TOTAL;
        int chunk = i >> 8, p = i & 255;
        // invert the interleave map: packed pos p -> (g, cc)
        int g, cc;
        if (p < 64)       { g = 0; cc = p; }
        else if (p < 192) { g = 1 + ((p - 64) & 1); cc = (p - 64) >> 1; }
        else              { g = 3; cc = p - 192; }
        const int ltab[7] = {0, 1, 1, 2, 2, 2, 2};
        const int ctab[7] = {0, 0, 64, 0, 64, 128, 192};
        biascat[i] = S.bg[ltab[chunk]][g][ctab[chunk] + cc];
    }
}

// x (fp32 [N][128]) -> bf16 [N][128]
__global__ void aconv(const float* __restrict__ A, ushort* __restrict__ O)
{
    int id = blockIdx.x * 256 + threadIdx.x;
    if (id >= GN_N * 16) return;
    int r = id >> 4, cc = id & 15;
    const float* src = A + (size_t)r * 128 + cc * 8;
    short8 h;
    #pragma unroll
    for (int j = 0; j < 8; ++j) h[j] = (short)f2bf_rne(src[j]);
    *(short8*)&O[(size_t)r * 128 + cc * 8] = h;
}

// GEMM: 128 rows x BC cols per block. A bf16; AMODE=0 copy-stage,
// AMODE=2 bf16 + leaky(0.01) stage. B hi/lo: 2 MFMAs per tile.
// Double-buffered LDS + async reg-stage: issue t+1 loads, compute t,
// write t+1, one barrier per K-step.
template<int BC, int AMODE>
__global__ __launch_bounds__((BC == 128) ? 512 : 256, 4) void gemm2(
    const ushort* __restrict__ Aptr, int lda,
    const ushort* __restrict__ Bh, const ushort* __restrict__ Bl,
    const float* __restrict__ bias,
    ushort* __restrict__ Obf, int ldo,
    int K)
{
    constexpr int NT = (BC == 128) ? 512 : 256;
    constexpr int ST = 34;    // LDS row stride (ushorts): 17 words, odd
    __shared__ ushort sA[2][128 * ST];
    __shared__ ushort sBh[2][BC * ST], sBl[2][BC * ST];

    const int tid  = threadIdx.x;
    const int w    = tid >> 6, lane = tid & 63;
    const int m    = lane & 15, quad = lane >> 4;
    const int row0 = blockIdx.x * 128;
    const int col0 = blockIdx.y * BC;
    const int wr   = (BC == 128) ? (w >> 1) * 32 : w * 32;
    const int wc   = (BC == 128) ? (w & 1) * 64 : 0;

    floatx4 acc[2][4];
    #pragma unroll
    for (int i = 0; i < 2; ++i)
        #pragma unroll
        for (int j = 0; j < 4; ++j) acc[i][j] = (floatx4){0.f, 0.f, 0.f, 0.f};

    // staging geometry
    const int ar   = (NT == 512) ? (tid >> 2) : (tid >> 1);
    const int ak   = (NT == 512) ? ((tid & 3) * 8) : ((tid & 1) * 16);
    const int bcol = tid >> 2;
    const int bk   = (tid & 3) * 8;
    const int arow = row0 + ar;
    const bool aok = arow < GN_N;

    short8 ra0, ra1, rbh, rbl;

    auto load_tile = [&](int k0) {
        if (aok) {
            const ushort* ap = Aptr + (size_t)arow * lda + k0 + ak;
            ra0 = *(const short8*)ap;
            if constexpr (NT == 256) ra1 = *(const short8*)(ap + 8);
        } else {
            #pragma unroll
            for (int j = 0; j < 8; ++j) { ra0[j] = 0; if constexpr (NT == 256) ra1[j] = 0; }
        }
        size_t off = (size_t)(col0 + bcol) * K + k0 + bk;
        rbh = *(const short8*)(Bh + off);
        rbl = *(const short8*)(Bl + off);
    };
    auto store_tile = [&](int buf) {
        short8 w0 = ra0, w1 = ra1;
        if constexpr (AMODE == 2) {
            #pragma unroll
            for (int j = 0; j < 8; ++j) {
                float f = bf2f((ushort)w0[j]); f = f > 0.f ? f : 0.01f * f;
                w0[j] = (short)f2bf_rne(f);
                if constexpr (NT == 256) {
                    float g = bf2f((ushort)w1[j]); g = g > 0.f ? g : 0.01f * g;
                    w1[j] = (short)f2bf_rne(g);
                }
            }
        }
        *(short8*)&sA[buf][ar * ST + ak] = w0;
        if constexpr (NT == 256) *(short8*)&sA[buf][ar * ST + ak + 8] = w1;
        *(short8*)&sBh[buf][bcol * ST + bk] = rbh;
        *(short8*)&sBl[buf][bcol * ST + bk] = rbl;
    };

    const int nt = K >> 5;
    load_tile(0);
    store_tile(0);
    __syncthreads();

    int cur = 0;
    for (int t = 0; t < nt; ++t) {
        if (t + 1 < nt) load_tile((t + 1) << 5);
        // ---- compute from buf[cur]: 2 MFMAs per tile ----
        short8 bhf[4], blf[4];
        #pragma unroll
        for (int ct = 0; ct < 4; ++ct) {
            bhf[ct] = *(const short8*)&sBh[cur][(wc + ct * 16 + m) * ST + quad * 8];
            blf[ct] = *(const short8*)&sBl[cur][(wc + ct * 16 + m) * ST + quad * 8];
        }
        #pragma unroll
        for (int rt = 0; rt < 2; ++rt) {
            short8 ahf = *(const short8*)&sA[cur][(wr + rt * 16 + m) * ST + quad * 8];
            #pragma unroll
            for (int ct = 0; ct < 4; ++ct) {
                acc[rt][ct] = __builtin_amdgcn_mfma_f32_16x16x32_bf16(ahf, bhf[ct], acc[rt][ct], 0, 0, 0);
                acc[rt][ct] = __builtin_amdgcn_mfma_f32_16x16x32_bf16(ahf, blf[ct], acc[rt][ct], 0, 0, 0);
            }
        }
        if (t + 1 < nt) {
            store_tile(cur ^ 1);
            __syncthreads();
            cur ^= 1;
        }
    }

    #pragma unroll
    for (int rt = 0; rt < 2; ++rt) {
        #pragma unroll
        for (int ct = 0; ct < 4; ++ct) {
            int ocol = col0 + wc + ct * 16 + m;
            float bb = bias[ocol];
            #pragma unroll
            for (int reg = 0; reg < 4; ++reg) {
                int orow = row0 + wr + rt * 16 + quad * 4 + reg;
                if (orow >= GN_N) continue;
                Obf[(size_t)orow * ldo + ocol] = f2bf_rne(acc[rt][ct][reg] + bb);
            }
        }
    }
}

// ---------------- CSR build ----------------
__global__ void zero_int(int* p, int n)
{
    int i = blockIdx.x * 256 + threadIdx.x;
    if (i < n) p[i] = 0;
}

__global__ void hist_kernel(const int* __restrict__ dst, int* __restrict__ deg)
{
    int e = blockIdx.x * 256 + threadIdx.x;
    if (e < GN_E) atomicAdd(&deg[dst[e]], 1);
}

__global__ void scan1(const int* __restrict__ deg, int* __restrict__ rp, int* __restrict__ bsums)
{
    __shared__ int s[256];
    int b = blockIdx.x, t = threadIdx.x;
    int i = b * 256 + t;
    int v = (i < GN_N) ? deg[i] : 0;
    s[t] = v;
    __syncthreads();
    for (int off = 1; off < 256; off <<= 1) {
        int x = (t >= off) ? s[t - off] : 0;
        __syncthreads();
        s[t] += x;
        __syncthreads();
    }
    if (i < GN_N) rp[i] = s[t] - v;
    if (t == 255) bsums[b] = s[255];
}

__global__ __launch_bounds__(512) void scan2(int* bsums, int nb)
{
    __shared__ int s[512];
    int t = threadIdx.x;
    int v = (t < nb) ? bsums[t] : 0;
    s[t] = v;
    __syncthreads();
    for (int off = 1; off < 512; off <<= 1) {
        int x = (t >= off) ? s[t - off] : 0;
        __syncthreads();
        s[t] += x;
        __syncthreads();
    }
    if (t < nb) bsums[t] = s[t] - v;
}

__global__ void scan3(const int* __restrict__ bsums, int* __restrict__ rp, int* __restrict__ cursor)
{
    int b = blockIdx.x, t = threadIdx.x;
    int i = b * 256 + t;
    if (i < GN_N) {
        int v = rp[i] + bsums[b];
        rp[i] = v; cursor[i] = v;
    }
    if (i == 0) rp[GN_N] = GN_E;
}

__global__ void scatter_kernel(
    const int* __restrict__ src, const int* __restrict__ dst,
    int* __restrict__ cursor, int* __restrict__ elist)
{
    int e = blockIdx.x * 256 + threadIdx.x;
    if (e >= GN_E) return;
    int d = dst[e];
    int pos = atomicAdd(&cursor[d], 1);
    elist[pos] = src[e];
}

__global__ void bounds_kernel(const int* __restrict__ batch, int* __restrict__ se)
{
    int i = blockIdx.x * 256 + threadIdx.x;
    if (i >= GN_N) return;
    int g = batch[i];
    if (i == 0 || batch[i - 1] != g) se[g] = i;
    if (i == GN_N - 1 || batch[i + 1] != g) se[32 + g] = i + 1;
}

__global__ void cnt_kernel(const int* __restrict__ se, float* __restrict__ cnt)
{
    int g = threadIdx.x;
    if (g < GN_G) cnt[g] = (float)(se[32 + g] - se[g]);
}

// Gbf[N][256] = [K(64) | Q0V0Q1V1..(128) | S(64)] bf16. acc seeds from S;
// out_i = S_i + sum relu(K[i]+Q[j])*V[j] -> bf16 Abf (ald/aoff). 4 nodes/wave,
// 8-edge batch (all loads independent), serial tail for deg>8.
__global__ __launch_bounds__(256, 2) void edge_gather_w(
    const ushort* __restrict__ Gbf, ushort* __restrict__ Abf, int ald, int aoff,
    const int* __restrict__ row_ptr, const int* __restrict__ elist)
{
    int w = threadIdx.x >> 6, c = threadIdx.x & 63;
    int n0 = blockIdx.x * 16 + w * 4;

    float k[4], acc[4];
    int beg[4], end[4];
    #pragma unroll
    for (int j = 0; j < 4; ++j) {
        int node = n0 + j;
        bool ok = node < GN_N;
        int nd = ok ? node : 0;
        beg[j] = row_ptr[nd];
        end[j] = ok ? row_ptr[nd + 1] : beg[j];
        k[j]   = bf2f(Gbf[(size_t)nd * 256 + c]);
        acc[j] = bf2f(Gbf[(size_t)nd * 256 + 192 + c]);
    }
    int s[32];
    #pragma unroll
    for (int j = 0; j < 4; ++j) {
        #pragma unroll
        for (int e = 0; e < 8; ++e) {
            int idx = beg[j] + e;
            s[j * 8 + e] = elist[idx < end[j] ? idx : 0];
        }
    }
    uint qv[32];
    #pragma unroll
    for (int je = 0; je < 32; ++je)
        qv[je] = *(const uint*)&Gbf[(size_t)s[je] * 256 + 64 + 2 * c];
    #pragma unroll
    for (int j = 0; j < 4; ++j) {
        #pragma unroll
        for (int e = 0; e < 8; ++e) {
            if (beg[j] + e < end[j]) {
                uint p = qv[j * 8 + e];
                float gt = k[j] + bf2f((ushort)(p & 0xffffu));
                if (gt > 0.f) acc[j] += gt * bf2f((ushort)(p >> 16));
            }
        }
    }
    #pragma unroll
    for (int j = 0; j < 4; ++j) {
        for (int i = beg[j] + 8; i < end[j]; ++i) {
            int ss = elist[i];
            uint p = *(const uint*)&Gbf[(size_t)ss * 256 + 64 + 2 * c];
            float gt = k[j] + bf2f((ushort)(p & 0xffffu));
            if (gt > 0.f) acc[j] += gt * bf2f((ushort)(p >> 16));
        }
    }
    #pragma unroll
    for (int j = 0; j < 4; ++j)
        if (n0 + j < GN_N) Abf[(size_t)(n0 + j) * ald + aoff + c] = f2bf_rne(acc[j]);
}

// Layer-3: gather + leaky + 16-node LDS reduce + striped run-length atomics.
__global__ __launch_bounds__(256, 2) void edge_gather_pool(
    const ushort* __restrict__ Gbf,
    const int* __restrict__ row_ptr, const int* __restrict__ elist,
    const int* __restrict__ batch,
    float* __restrict__ sums, int c0)
{
    __shared__ float red[16][64];
    __shared__ int gid[16];
    int w = threadIdx.x >> 6, c = threadIdx.x & 63;
    int n0 = blockIdx.x * 16 + w * 4;

    float k[4], acc[4];
    int beg[4], end[4];
    #pragma unroll
    for (int j = 0; j < 4; ++j) {
        int node = n0 + j;
        bool ok = node < GN_N;
        int nd = ok ? node : 0;
        beg[j] = row_ptr[nd];
        end[j] = ok ? row_ptr[nd + 1] : beg[j];
        k[j]   = bf2f(Gbf[(size_t)nd * 256 + c]);
        acc[j] = ok ? bf2f(Gbf[(size_t)nd * 256 + 192 + c]) : 0.f;
    }
    int s[32];
    #pragma unroll
    for (int j = 0; j < 4; ++j) {
        #pragma unroll
        for (int e = 0; e < 8; ++e) {
            int idx = beg[j] + e;
            s[j * 8 + e] = elist[idx < end[j] ? idx : 0];
        }
    }
    uint qv[32];
    #pragma unroll
    for (int je = 0; je < 32; ++je)
        qv[je] = *(const uint*)&Gbf[(size_t)s[je] * 256 + 64 + 2 * c];
    #pragma unroll
    for (int j = 0; j < 4; ++j) {
        #pragma unroll
        for (int e = 0; e < 8; ++e) {
            if (beg[j] + e < end[j]) {
                uint p = qv[j * 8 + e];
                float gt = k[j] + bf2f((ushort)(p & 0xffffu));
                if (gt > 0.f) acc[j] += gt * bf2f((ushort)(p >> 16));
            }
        }
    }
    #pragma unroll
    for (int j = 0; j < 4; ++j) {
        for (int i = beg[j] + 8; i < end[j]; ++i) {
            int ss = elist[i];
            uint p = *(const uint*)&Gbf[(size_t)ss * 256 + 64 + 2 * c];
            float gt = k[j] + bf2f((ushort)(p & 0xffffu));
            if (gt > 0.f) acc[j] += gt * bf2f((ushort)(p >> 16));
        }
    }
    #pragma unroll
    for (int j = 0; j < 4; ++j) {
        float a = acc[j];
        red[w * 4 + j][c] = a > 0.f ? a : 0.01f * a;
    }
    if (c < 4) {
        int node = n0 + c;
        gid[w * 4 + c] = (node < GN_N) ? batch[node] : -1;
    }
    __syncthreads();
    if (w == 0) {
        int stripe = blockIdx.x & 31;
        int i = 0;
        while (i < 16) {
            int gg = gid[i];
            float sum = 0.f;
            int j = i;
            while (j < 16 && gid[j] == gg) { sum += red[j][c]; ++j; }
            if (gg >= 0) atomicAdd(&sums[(size_t)(stripe * GN_G + gg) * 256 + c0 + c], sum);
            i = j;
        }
    }
}

__global__ void zero_sums(float* sums)
{
    int i = blockIdx.x * 256 + threadIdx.x;
    if (i < 32 * GN_G * 256) sums[i] = 0.0f;
}

// One block per graph: reduce 32 stripes; Pl = sums[g]/cnt[g];
// Pg = Pl @ Wl3 + bl3; BN-MLP chain.
__global__ __launch_bounds__(256) void mlp_kernel(
    const float* __restrict__ sums, const float* __restrict__ cnt,
    const float* __restrict__ Wl3, const float* __restrict__ bl3,
    const float* __restrict__ W1, const float* __restrict__ b1,
    const float* __restrict__ Wh, const float* __restrict__ bh,
    const float* __restrict__ Wo, const float* __restrict__ bo,
    const float* __restrict__ gamma, const float* __restrict__ beta,
    const float* __restrict__ mean, const float* __restrict__ var,
    float* __restrict__ out)
{
    __shared__ float sp[256];
    __shared__ float pg[256];
    __shared__ float h0[64], h1[64];
    const int g = blockIdx.x;
    const int t = threadIdx.x;
    const float inv = 1.0f / fmaxf(cnt[g], 1.0f);

    {
        float acc = 0.f;
        #pragma unroll 8
        for (int st = 0; st < 32; ++st)
            acc += sums[(size_t)(st * GN_G + g) * 256 + t];
        sp[t] = acc * inv;
    }
    __syncthreads();

    {
        float a0 = 0.f, a1 = 0.f, a2 = 0.f, a3 = 0.f;
        #pragma unroll 4
        for (int k = 0; k < 256; k += 4) {
            a0 += sp[k + 0] * Wl3[(k + 0) * 256 + t];
            a1 += sp[k + 1] * Wl3[(k + 1) * 256 + t];
            a2 += sp[k + 2] * Wl3[(k + 2) * 256 + t];
            a3 += sp[k + 3] * Wl3[(k + 3) * 256 + t];
        }
        pg[t] = bl3[t] + ((a0 + a1) + (a2 + a3));
    }
    __syncthreads();

    if (t < 64) {
        float a0 = 0.f, a1 = 0.f, a2 = 0.f, a3 = 0.f;
        #pragma unroll 4
        for (int k = 0; k < 256; k += 4) {
            a0 += pg[k + 0] * W1[(k + 0) * 64 + t];
            a1 += pg[k + 1] * W1[(k + 1) * 64 + t];
            a2 += pg[k + 2] * W1[(k + 2) * 64 + t];
            a3 += pg[k + 3] * W1[(k + 3) * 64 + t];
        }
        float acc = b1[t] + ((a0 + a1) + (a2 + a3));
        float sc = gamma[t] * rsqrtf(var[t] + 1e-5f);
        acc = (acc - mean[t]) * sc + beta[t];
        h0[t] = fmaxf(acc, 0.0f);
    }
    __syncthreads();

    for (int L = 0; L < 3; ++L) {
        const float* W  = Wh + L * 64 * 64;
        const float* hin  = (L & 1) ? h1 : h0;
        float*       hout = (L & 1) ? h0 : h1;
        if (t < 64) {
            const float* ga = gamma + (L + 1) * 64;
            const float* be = beta  + (L + 1) * 64;
            const float* me = mean  + (L + 1) * 64;
            const float* va = var   + (L + 1) * 64;
            float a0 = 0.f, a1 = 0.f, a2 = 0.f, a3 = 0.f;
            #pragma unroll 4
            for (int k = 0; k < 64; k += 4) {
                a0 += hin[k + 0] * W[(k + 0) * 64 + t];
                a1 += hin[k + 1] * W[(k + 1) * 64 + t];
                a2 += hin[k + 2] * W[(k + 2) * 64 + t];
                a3 += hin[k + 3] * W[(k + 3) * 64 + t];
            }
            float acc = (bh + L * 64)[t] + ((a0 + a1) + (a2 + a3));
            float sc = ga[t] * rsqrtf(va[t] + 1e-5f);
            acc = (acc - me[t]) * sc + be[t];
            hout[t] = fmaxf(acc, 0.0f);
        }
        __syncthreads();
    }

    if (t < 8) {
        const float* hf = h1;
        float acc = bo[t];
        for (int k = 0; k < 64; ++k) acc += hf[k] * Wo[k * 8 + t];
        out[g * 8 + t] = acc;
    }
}

extern "C" void kernel_launch(void* const* d_in, const int* in_sizes, int n_in,
                              void* d_out, int out_size, void* d_ws, size_t ws_size,
                              hipStream_t stream)
{
    const int N = GN_N, E = GN_E;
    const float* x          = (const float*)d_in[0];
    const int*   edge_index = (const int*)d_in[1];
    const int*   batch      = (const int*)d_in[2];
    const int*   src = edge_index;
    const int*   dst = edge_index + E;
    auto F = [&](int i) { return (const float*)d_in[i]; };

    // ---- workspace layout ----
    float* ws    = (float*)d_ws;
    float* sums  = ws;                          // 32 stripes x 32 x 256
    float* cnt   = sums + 32 * GN_G * 256;      // 32
    float* bcat  = cnt + GN_G;                  // 7 x 256
    ushort* Whi  = (ushort*)(bcat + 1792);
    ushort* Wlo  = Whi + W_TOTAL;
    ushort* xbf  = Wlo + W_TOTAL;               // N x 128 bf16
    ushort* hAbf = xbf + (size_t)N * 128;       // N x 64 bf16
    ushort* hBbf = hAbf + (size_t)N * 64;       // N x 128 bf16
    ushort* Gbf  = hBbf + (size_t)N * 128;      // N x 256 bf16 [K|QV|S]
    ushort* Abf  = Gbf + (size_t)N * 256;       // N x 128 bf16 (pre-Wl acts)
    int* deg     = (int*)(Abf + (size_t)N * 128);
    int* cursor  = deg + N;
    int* row_ptr = cursor + N;                  // N+1
    int* elist   = row_ptr + (N + 1);           // E
    int* bsums   = elist + E;                   // 512
    int* se      = bsums + 512;                 // 64

    size_t need = (size_t)((char*)(se + 64) - (char*)ws);
    if (ws_size < need) return;

    // ---- CSR build + graph bounds ----
    const int eb = (E + 255) / 256;
    const int nb = (N + 255) / 256;
    zero_int<<<nb, 256, 0, stream>>>(deg, N);
    zero_int<<<1, 256, 0, stream>>>(se, 64);
    hist_kernel<<<eb, 256, 0, stream>>>(dst, deg);
    scan1<<<nb, 256, 0, stream>>>(deg, row_ptr, bsums);
    scan2<<<1, 512, 0, stream>>>(bsums, nb);
    scan3<<<nb, 256, 0, stream>>>(bsums, row_ptr, cursor);
    scatter_kernel<<<eb, 256, 0, stream>>>(src, dst, cursor, elist);
    bounds_kernel<<<nb, 256, 0, stream>>>(batch, se);
    cnt_kernel<<<1, 64, 0, stream>>>(se, cnt);

    // ---- weight + input pre-conversion ----
    WSrc S;
    for (int l = 0; l < 3; ++l) {
        int base = 3 + l * 10;
        for (int g = 0; g < 4; ++g) S.Wg[l][g] = F(base + g);
        for (int g = 0; g < 4; ++g) S.bg[l][g] = F(base + 4 + g);
    }
    S.Wl[0] = F(11); S.Wl[1] = F(21);
    wconv<<<(W_TOTAL + 1792 + 255) / 256, 256, 0, stream>>>(S, Whi, Wlo, bcat);
    aconv<<<(N * 16 + 255) / 256, 256, 0, stream>>>(x, xbf);

    zero_sums<<<(32 * GN_G * 256 + 255) / 256, 256, 0, stream>>>(sums);

    const int rb = (N + 127) / 128;
    const int gatherBlocks = (N + 15) / 16;

    // ---- layer 1 ----
    gemm2<128, 0><<<dim3(rb, 2), 512, 0, stream>>>(
        xbf, 128, Whi, Wlo, bcat, Gbf, 256, 128);
    edge_gather_w<<<gatherBlocks, 256, 0, stream>>>(Gbf, Abf, 64, 0, row_ptr, elist);
    gemm2<64, 2><<<dim3(rb, 1), 256, 0, stream>>>(
        Abf, 64, Whi + WOFF_WL1, Wlo + WOFF_WL1, F(12), hAbf, 64, 64);

    // ---- layer 2 (2 chunks of gates, then one Wl2) ----
    for (int ch = 0; ch < 2; ++ch) {
        size_t go = WOFF_L2 + (size_t)ch * 16384;
        gemm2<128, 0><<<dim3(rb, 2), 512, 0, stream>>>(
            hAbf, 64, Whi + go, Wlo + go, bcat + (1 + ch) * 256, Gbf, 256, 64);
        edge_gather_w<<<gatherBlocks, 256, 0, stream>>>(
            Gbf, Abf, 128, ch * 64, row_ptr, elist);
    }
    gemm2<128, 2><<<dim3(rb, 1), 512, 0, stream>>>(
        Abf, 128, Whi + WOFF_WL2, Wlo + WOFF_WL2, F(22), hBbf, 128, 128);

    // ---- layer 3 (4 chunks, fused pool) ----
    for (int ch = 0; ch < 4; ++ch) {
        size_t go = WOFF_L3 + (size_t)ch * 32768;
        gemm2<128, 0><<<dim3(rb, 2), 512, 0, stream>>>(
            hBbf, 128, Whi + go, Wlo + go, bcat + (3 + ch) * 256, Gbf, 256, 128);
        edge_gather_pool<<<gatherBlocks, 256, 0, stream>>>(
            Gbf, row_ptr, elist, batch, sums, ch * 64);
    }

    mlp_kernel<<<GN_G, 256, 0, stream>>>(sums, cnt, F(31), F(32),
                                         F(33), F(34), F(35), F(36), F(37), F(38),
                                         F(39), F(40), F(41), F(42),
                                         (float*)d_out);
}

// Round 4
// 658.648 us; speedup vs baseline: 1.1163x; 1.1163x over previous
//
#include <hip/hip_runtime.h>
#include <hip/hip_bf16.h>

// ---------------------------------------------------------------------------
// QuadraticGNN: 3x ResGatedGraphConv (ReLU gate, LeakyReLU 0.01, linear Wl)
//               -> global mean pool (32 graphs) -> 5-layer MLP with BN.
// Round 16:
//   - R15 post-mortem: explicit LDS dbuf REGRESSED (occupancy 44->29%;
//     VGPR+AGPR=84 is reg-quantum capped at 4 waves/SIMD, so the extra
//     LDS bought nothing). Reverted gemm2 to R14 single-buffer.
//   - Attack the serial dispatch chain instead (29 dispatches, ~150us of
//     drain/ramp): L2 gates = ONE 512-col gemm + ONE dual-channel gather
//     (was 2+2); L3 = 2x512-col groups (was 4+4); zero_sums folded into
//     aconv. 29 -> 21 dispatches; elist/row_ptr/batch gather traffic for
//     L2/L3 halved; dual gathers have 64 independent QV loads in flight.
//   - Weight/bias column permutes all done in wconv (gemm untouched).
// ---------------------------------------------------------------------------

#define GN_N 100000
#define GN_E 300000
#define GN_G 32

typedef __attribute__((ext_vector_type(8))) short short8;
typedef __attribute__((ext_vector_type(4))) float floatx4;

__device__ inline ushort f2bf_rne(float f) {
    unsigned u = __float_as_uint(f);
    unsigned r = u + 0x7fffu + ((u >> 16) & 1u);
    return (ushort)(r >> 16);
}
__device__ inline float bf2f(ushort h) { return __uint_as_float(((unsigned)h) << 16); }

// W-array layout (ushort offsets), k-major [col][K] per segment.
// L1: 256 cols x K128 [K64|QV128|S64]. L2: 512 cols x K64 [K128|QV256|S128].
// L3: 2 groups x 512 cols x K128 [K128|QV256|S128].
#define WOFF_L2   32768
#define WOFF_L3   65536
#define WOFF_WL1  196608
#define WOFF_WL2  200704
#define W_TOTAL   217088

struct WSrc {
    const float* Wg[3][4];
    const float* Wl[2];
    const float* bg[3][4];
};

__global__ void wconv(WSrc S, ushort* __restrict__ hi, ushort* __restrict__ lo,
                      float* __restrict__ biascat)
{
    int id = blockIdx.x * 256 + threadIdx.x;
    if (id < 196608) {
        int l, base, ci, co;
        if (id < 32768)      { l = 0; base = 0;        ci = 128; co = 64;  }
        else if (id < 65536) { l = 1; base = WOFF_L2;  ci = 64;  co = 128; }
        else                 { l = 2; base = WOFF_L3;  ci = 128; co = 256; }
        int r  = id - base;
        int g  = r / (co * ci);
        int r2 = r - g * co * ci;
        int c  = r2 / ci;
        int k  = r2 - c * ci;
        float v = S.Wg[l][g][k * co + c];
        int dst;
        if (l == 0) {
            int cc = c;  // co=64
            int colIdx = (g == 0) ? cc : (g == 3) ? (192 + cc) : (64 + 2 * cc + (g - 1));
            dst = colIdx * 128 + k;
        } else if (l == 1) {
            int cc = c;  // co=128, single 512 group
            int colIdx = (g == 0) ? cc : (g == 3) ? (384 + cc) : (128 + 2 * cc + (g - 1));
            dst = WOFF_L2 + colIdx * 64 + k;
        } else {
            int ch = c >> 7, cc = c & 127;  // co=256 -> 2 groups of 128
            int colIdx = (g == 0) ? cc : (g == 3) ? (384 + cc) : (128 + 2 * cc + (g - 1));
            dst = WOFF_L3 + ch * (512 * 128) + colIdx * 128 + k;
        }
        ushort h = f2bf_rne(v);
        hi[dst] = h; lo[dst] = f2bf_rne(v - bf2f(h));
    } else if (id < 196608 + 4096) {
        int r = id - 196608;
        int c = r >> 6, k = r & 63;
        float v = S.Wl[0][k * 64 + c];
        int dst = WOFF_WL1 + c * 64 + k;
        ushort h = f2bf_rne(v);
        hi[dst] = h; lo[dst] = f2bf_rne(v - bf2f(h));
    } else if (id < W_TOTAL) {
        int r = id - WOFF_WL2;
        int c = r >> 7, k2 = r & 127;
        float v = S.Wl[1][k2 * 128 + c];
        int dst = WOFF_WL2 + c * 128 + k2;
        ushort h = f2bf_rne(v);
        hi[dst] = h; lo[dst] = f2bf_rne(v - bf2f(h));
    } else if (id < W_TOTAL + 1792) {
        // biascat: [0,256) L1 | [256,768) L2 | [768,1792) L3 (2 x 512)
        int i = id - W_TOTAL;
        int l, p, ch = 0;
        if (i < 256)      { l = 0; p = i; }
        else if (i < 768) { l = 1; p = i - 256; }
        else              { l = 2; int r = i - 768; ch = r >> 9; p = r & 511; }
        int GW = (l == 0) ? 64 : 128;
        int g, cc;
        if (p < GW)           { g = 0; cc = p; }
        else if (p < 3 * GW)  { g = 1 + ((p - GW) & 1); cc = (p - GW) >> 1; }
        else                  { g = 3; cc = p - 3 * GW; }
        biascat[i] = S.bg[l][g][ch * 128 + cc];
    }
}

// x (fp32 [N][128]) -> bf16 [N][128]; also zeroes the striped pool sums.
__global__ void aconv(const float* __restrict__ A, ushort* __restrict__ O,
                      float* __restrict__ sums)
{
    int id = blockIdx.x * 256 + threadIdx.x;
    if (id < 32 * GN_G * 256) sums[id] = 0.0f;
    if (id >= GN_N * 16) return;
    int r = id >> 4, cc = id & 15;
    const float* src = A + (size_t)r * 128 + cc * 8;
    short8 h;
    #pragma unroll
    for (int j = 0; j < 8; ++j) h[j] = (short)f2bf_rne(src[j]);
    *(short8*)&O[(size_t)r * 128 + cc * 8] = h;
}

// GEMM: 128 rows x BC cols per block. A bf16; AMODE=0 copy-stage,
// AMODE=2 bf16 + leaky(0.01) stage. B hi/lo: 2 MFMAs per tile.
// Single-buffer LDS (R14 structure; dbuf regressed occupancy in R15).
template<int BC, int AMODE>
__global__ __launch_bounds__((BC == 128) ? 512 : 256, 4) void gemm2(
    const ushort* __restrict__ Aptr, int lda,
    const ushort* __restrict__ Bh, const ushort* __restrict__ Bl,
    const float* __restrict__ bias,
    ushort* __restrict__ Obf, int ldo,
    int K)
{
    constexpr int NT = (BC == 128) ? 512 : 256;
    constexpr int ST = 34;    // LDS row stride (ushorts): 17 words, odd
    __shared__ ushort sA[128 * ST];
    __shared__ ushort sBh[BC * ST], sBl[BC * ST];

    const int tid  = threadIdx.x;
    const int w    = tid >> 6, lane = tid & 63;
    const int m    = lane & 15, quad = lane >> 4;
    const int row0 = blockIdx.x * 128;
    const int col0 = blockIdx.y * BC;
    const int wr   = (BC == 128) ? (w >> 1) * 32 : w * 32;
    const int wc   = (BC == 128) ? (w & 1) * 64 : 0;

    floatx4 acc[2][4];
    #pragma unroll
    for (int i = 0; i < 2; ++i)
        #pragma unroll
        for (int j = 0; j < 4; ++j) acc[i][j] = (floatx4){0.f, 0.f, 0.f, 0.f};

    for (int k0 = 0; k0 < K; k0 += 32) {
        // ---- stage A ----
        if constexpr (NT == 512) {
            const int ar = tid >> 2, ak = (tid & 3) * 8;
            const int arow = row0 + ar;
            short8 a0;
            if (arow < GN_N) {
                const ushort* ap = Aptr + (size_t)arow * lda + k0 + ak;
                a0 = *(const short8*)ap;
                if constexpr (AMODE == 2) {
                    #pragma unroll
                    for (int j = 0; j < 8; ++j) {
                        float f = bf2f((ushort)a0[j]);
                        f = f > 0.f ? f : 0.01f * f;
                        a0[j] = (short)f2bf_rne(f);
                    }
                }
            } else {
                #pragma unroll
                for (int j = 0; j < 8; ++j) a0[j] = 0;
            }
            *(short8*)&sA[ar * ST + ak] = a0;
        } else {
            const int ar = tid >> 1, ak = (tid & 1) * 16;
            const int arow = row0 + ar;
            short8 a0, a1;
            if (arow < GN_N) {
                const ushort* ap = Aptr + (size_t)arow * lda + k0 + ak;
                a0 = *(const short8*)ap;
                a1 = *(const short8*)(ap + 8);
                if constexpr (AMODE == 2) {
                    #pragma unroll
                    for (int j = 0; j < 8; ++j) {
                        float f = bf2f((ushort)a0[j]); f = f > 0.f ? f : 0.01f * f;
                        a0[j] = (short)f2bf_rne(f);
                        float g = bf2f((ushort)a1[j]); g = g > 0.f ? g : 0.01f * g;
                        a1[j] = (short)f2bf_rne(g);
                    }
                }
            } else {
                #pragma unroll
                for (int j = 0; j < 8; ++j) { a0[j] = 0; a1[j] = 0; }
            }
            *(short8*)&sA[ar * ST + ak]     = a0;
            *(short8*)&sA[ar * ST + ak + 8] = a1;
        }
        // ---- stage B (NT/4 == BC in both instantiations) ----
        {
            const int col = tid >> 2, bk = (tid & 3) * 8;
            size_t off = (size_t)(col0 + col) * K + k0 + bk;
            *(short8*)&sBh[col * ST + bk] = *(const short8*)(Bh + off);
            *(short8*)&sBl[col * ST + bk] = *(const short8*)(Bl + off);
        }
        __syncthreads();
        // ---- compute: 2 MFMAs per tile ----
        short8 bhf[4], blf[4];
        #pragma unroll
        for (int ct = 0; ct < 4; ++ct) {
            bhf[ct] = *(const short8*)&sBh[(wc + ct * 16 + m) * ST + quad * 8];
            blf[ct] = *(const short8*)&sBl[(wc + ct * 16 + m) * ST + quad * 8];
        }
        #pragma unroll
        for (int rt = 0; rt < 2; ++rt) {
            short8 ahf = *(const short8*)&sA[(wr + rt * 16 + m) * ST + quad * 8];
            #pragma unroll
            for (int ct = 0; ct < 4; ++ct) {
                acc[rt][ct] = __builtin_amdgcn_mfma_f32_16x16x32_bf16(ahf, bhf[ct], acc[rt][ct], 0, 0, 0);
                acc[rt][ct] = __builtin_amdgcn_mfma_f32_16x16x32_bf16(ahf, blf[ct], acc[rt][ct], 0, 0, 0);
            }
        }
        __syncthreads();
    }

    #pragma unroll
    for (int rt = 0; rt < 2; ++rt) {
        #pragma unroll
        for (int ct = 0; ct < 4; ++ct) {
            int ocol = col0 + wc + ct * 16 + m;
            float bb = bias[ocol];
            #pragma unroll
            for (int reg = 0; reg < 4; ++reg) {
                int orow = row0 + wr + rt * 16 + quad * 4 + reg;
                if (orow >= GN_N) continue;
                Obf[(size_t)orow * ldo + ocol] = f2bf_rne(acc[rt][ct][reg] + bb);
            }
        }
    }
}

// ---------------- CSR build ----------------
__global__ void zero_int(int* p, int n)
{
    int i = blockIdx.x * 256 + threadIdx.x;
    if (i < n) p[i] = 0;
}

__global__ void hist_kernel(const int* __restrict__ dst, int* __restrict__ deg)
{
    int e = blockIdx.x * 256 + threadIdx.x;
    if (e < GN_E) atomicAdd(&deg[dst[e]], 1);
}

__global__ void scan1(const int* __restrict__ deg, int* __restrict__ rp, int* __restrict__ bsums)
{
    __shared__ int s[256];
    int b = blockIdx.x, t = threadIdx.x;
    int i = b * 256 + t;
    int v = (i < GN_N) ? deg[i] : 0;
    s[t] = v;
    __syncthreads();
    for (int off = 1; off < 256; off <<= 1) {
        int x = (t >= off) ? s[t - off] : 0;
        __syncthreads();
        s[t] += x;
        __syncthreads();
    }
    if (i < GN_N) rp[i] = s[t] - v;
    if (t == 255) bsums[b] = s[255];
}

__global__ __launch_bounds__(512) void scan2(int* bsums, int nb)
{
    __shared__ int s[512];
    int t = threadIdx.x;
    int v = (t < nb) ? bsums[t] : 0;
    s[t] = v;
    __syncthreads();
    for (int off = 1; off < 512; off <<= 1) {
        int x = (t >= off) ? s[t - off] : 0;
        __syncthreads();
        s[t] += x;
        __syncthreads();
    }
    if (t < nb) bsums[t] = s[t] - v;
}

__global__ void scan3(const int* __restrict__ bsums, int* __restrict__ rp, int* __restrict__ cursor)
{
    int b = blockIdx.x, t = threadIdx.x;
    int i = b * 256 + t;
    if (i < GN_N) {
        int v = rp[i] + bsums[b];
        rp[i] = v; cursor[i] = v;
    }
    if (i == 0) rp[GN_N] = GN_E;
}

__global__ void scatter_kernel(
    const int* __restrict__ src, const int* __restrict__ dst,
    int* __restrict__ cursor, int* __restrict__ elist)
{
    int e = blockIdx.x * 256 + threadIdx.x;
    if (e >= GN_E) return;
    int d = dst[e];
    int pos = atomicAdd(&cursor[d], 1);
    elist[pos] = src[e];
}

__global__ void bounds_kernel(const int* __restrict__ batch, int* __restrict__ se)
{
    int i = blockIdx.x * 256 + threadIdx.x;
    if (i >= GN_N) return;
    int g = batch[i];
    if (i == 0 || batch[i - 1] != g) se[g] = i;
    if (i == GN_N - 1 || batch[i + 1] != g) se[32 + g] = i + 1;
}

__global__ void cnt_kernel(const int* __restrict__ se, float* __restrict__ cnt)
{
    int g = threadIdx.x;
    if (g < GN_G) cnt[g] = (float)(se[32 + g] - se[g]);
}

// Layer-1 gather. Gbf row 256 = [K64|QV128|S64]. 4 nodes/wave, 8-edge batch.
__global__ __launch_bounds__(256, 2) void edge_gather_w(
    const ushort* __restrict__ Gbf, ushort* __restrict__ Abf,
    const int* __restrict__ row_ptr, const int* __restrict__ elist)
{
    int w = threadIdx.x >> 6, c = threadIdx.x & 63;
    int n0 = blockIdx.x * 16 + w * 4;

    float k[4], acc[4];
    int beg[4], end[4];
    #pragma unroll
    for (int j = 0; j < 4; ++j) {
        int node = n0 + j;
        bool ok = node < GN_N;
        int nd = ok ? node : 0;
        beg[j] = row_ptr[nd];
        end[j] = ok ? row_ptr[nd + 1] : beg[j];
        k[j]   = bf2f(Gbf[(size_t)nd * 256 + c]);
        acc[j] = bf2f(Gbf[(size_t)nd * 256 + 192 + c]);
    }
    int s[32];
    #pragma unroll
    for (int j = 0; j < 4; ++j) {
        #pragma unroll
        for (int e = 0; e < 8; ++e) {
            int idx = beg[j] + e;
            s[j * 8 + e] = elist[idx < end[j] ? idx : 0];
        }
    }
    uint qv[32];
    #pragma unroll
    for (int je = 0; je < 32; ++je)
        qv[je] = *(const uint*)&Gbf[(size_t)s[je] * 256 + 64 + 2 * c];
    #pragma unroll
    for (int j = 0; j < 4; ++j) {
        #pragma unroll
        for (int e = 0; e < 8; ++e) {
            if (beg[j] + e < end[j]) {
                uint p = qv[j * 8 + e];
                float gt = k[j] + bf2f((ushort)(p & 0xffffu));
                if (gt > 0.f) acc[j] += gt * bf2f((ushort)(p >> 16));
            }
        }
    }
    #pragma unroll
    for (int j = 0; j < 4; ++j) {
        for (int i = beg[j] + 8; i < end[j]; ++i) {
            int ss = elist[i];
            uint p = *(const uint*)&Gbf[(size_t)ss * 256 + 64 + 2 * c];
            float gt = k[j] + bf2f((ushort)(p & 0xffffu));
            if (gt > 0.f) acc[j] += gt * bf2f((ushort)(p >> 16));
        }
    }
    #pragma unroll
    for (int j = 0; j < 4; ++j)
        if (n0 + j < GN_N) Abf[(size_t)(n0 + j) * 64 + c] = f2bf_rne(acc[j]);
}

// Layer-2 dual gather. Gbf row 512 = [K128|QV256|S128]; thread handles
// channels c and 64+c. Writes Abf[N][128].
__global__ __launch_bounds__(256, 2) void edge_gather_w2(
    const ushort* __restrict__ Gbf, ushort* __restrict__ Abf,
    const int* __restrict__ row_ptr, const int* __restrict__ elist)
{
    int w = threadIdx.x >> 6, c = threadIdx.x & 63;
    int n0 = blockIdx.x * 16 + w * 4;

    float k0[4], k1[4], a0[4], a1[4];
    int beg[4], end[4];
    #pragma unroll
    for (int j = 0; j < 4; ++j) {
        int node = n0 + j;
        bool ok = node < GN_N;
        int nd = ok ? node : 0;
        beg[j] = row_ptr[nd];
        end[j] = ok ? row_ptr[nd + 1] : beg[j];
        size_t b = (size_t)nd * 512;
        k0[j] = bf2f(Gbf[b + c]);
        k1[j] = bf2f(Gbf[b + 64 + c]);
        a0[j] = bf2f(Gbf[b + 384 + c]);
        a1[j] = bf2f(Gbf[b + 448 + c]);
    }
    int s[32];
    #pragma unroll
    for (int j = 0; j < 4; ++j) {
        #pragma unroll
        for (int e = 0; e < 8; ++e) {
            int idx = beg[j] + e;
            s[j * 8 + e] = elist[idx < end[j] ? idx : 0];
        }
    }
    uint qv0[32], qv1[32];
    #pragma unroll
    for (int je = 0; je < 32; ++je) {
        size_t b = (size_t)s[je] * 512;
        qv0[je] = *(const uint*)&Gbf[b + 128 + 2 * c];
        qv1[je] = *(const uint*)&Gbf[b + 256 + 2 * c];
    }
    #pragma unroll
    for (int j = 0; j < 4; ++j) {
        #pragma unroll
        for (int e = 0; e < 8; ++e) {
            if (beg[j] + e < end[j]) {
                uint p = qv0[j * 8 + e];
                float gt = k0[j] + bf2f((ushort)(p & 0xffffu));
                if (gt > 0.f) a0[j] += gt * bf2f((ushort)(p >> 16));
                uint q = qv1[j * 8 + e];
                float gu = k1[j] + bf2f((ushort)(q & 0xffffu));
                if (gu > 0.f) a1[j] += gu * bf2f((ushort)(q >> 16));
            }
        }
    }
    #pragma unroll
    for (int j = 0; j < 4; ++j) {
        for (int i = beg[j] + 8; i < end[j]; ++i) {
            size_t b = (size_t)elist[i] * 512;
            uint p = *(const uint*)&Gbf[b + 128 + 2 * c];
            uint q = *(const uint*)&Gbf[b + 256 + 2 * c];
            float gt = k0[j] + bf2f((ushort)(p & 0xffffu));
            if (gt > 0.f) a0[j] += gt * bf2f((ushort)(p >> 16));
            float gu = k1[j] + bf2f((ushort)(q & 0xffffu));
            if (gu > 0.f) a1[j] += gu * bf2f((ushort)(q >> 16));
        }
    }
    #pragma unroll
    for (int j = 0; j < 4; ++j)
        if (n0 + j < GN_N) {
            Abf[(size_t)(n0 + j) * 128 + c]      = f2bf_rne(a0[j]);
            Abf[(size_t)(n0 + j) * 128 + 64 + c] = f2bf_rne(a1[j]);
        }
}

// Layer-3 dual gather + leaky + pool. Gbf row 512; channels c0+c, c0+64+c.
__global__ __launch_bounds__(256, 2) void edge_gather_pool2(
    const ushort* __restrict__ Gbf,
    const int* __restrict__ row_ptr, const int* __restrict__ elist,
    const int* __restrict__ batch,
    float* __restrict__ sums, int c0)
{
    __shared__ float red[16][128];
    __shared__ int gid[16];
    int w = threadIdx.x >> 6, c = threadIdx.x & 63;
    int n0 = blockIdx.x * 16 + w * 4;

    float k0[4], k1[4], a0[4], a1[4];
    int beg[4], end[4];
    #pragma unroll
    for (int j = 0; j < 4; ++j) {
        int node = n0 + j;
        bool ok = node < GN_N;
        int nd = ok ? node : 0;
        beg[j] = row_ptr[nd];
        end[j] = ok ? row_ptr[nd + 1] : beg[j];
        size_t b = (size_t)nd * 512;
        k0[j] = bf2f(Gbf[b + c]);
        k1[j] = bf2f(Gbf[b + 64 + c]);
        a0[j] = ok ? bf2f(Gbf[b + 384 + c]) : 0.f;
        a1[j] = ok ? bf2f(Gbf[b + 448 + c]) : 0.f;
    }
    int s[32];
    #pragma unroll
    for (int j = 0; j < 4; ++j) {
        #pragma unroll
        for (int e = 0; e < 8; ++e) {
            int idx = beg[j] + e;
            s[j * 8 + e] = elist[idx < end[j] ? idx : 0];
        }
    }
    uint qv0[32], qv1[32];
    #pragma unroll
    for (int je = 0; je < 32; ++je) {
        size_t b = (size_t)s[je] * 512;
        qv0[je] = *(const uint*)&Gbf[b + 128 + 2 * c];
        qv1[je] = *(const uint*)&Gbf[b + 256 + 2 * c];
    }
    #pragma unroll
    for (int j = 0; j < 4; ++j) {
        #pragma unroll
        for (int e = 0; e < 8; ++e) {
            if (beg[j] + e < end[j]) {
                uint p = qv0[j * 8 + e];
                float gt = k0[j] + bf2f((ushort)(p & 0xffffu));
                if (gt > 0.f) a0[j] += gt * bf2f((ushort)(p >> 16));
                uint q = qv1[j * 8 + e];
                float gu = k1[j] + bf2f((ushort)(q & 0xffffu));
                if (gu > 0.f) a1[j] += gu * bf2f((ushort)(q >> 16));
            }
        }
    }
    #pragma unroll
    for (int j = 0; j < 4; ++j) {
        for (int i = beg[j] + 8; i < end[j]; ++i) {
            size_t b = (size_t)elist[i] * 512;
            uint p = *(const uint*)&Gbf[b + 128 + 2 * c];
            uint q = *(const uint*)&Gbf[b + 256 + 2 * c];
            float gt = k0[j] + bf2f((ushort)(p & 0xffffu));
            if (gt > 0.f) a0[j] += gt * bf2f((ushort)(p >> 16));
            float gu = k1[j] + bf2f((ushort)(q & 0xffffu));
            if (gu > 0.f) a1[j] += gu * bf2f((ushort)(q >> 16));
        }
    }
    #pragma unroll
    for (int j = 0; j < 4; ++j) {
        float x = a0[j], y = a1[j];
        red[w * 4 + j][c]      = x > 0.f ? x : 0.01f * x;
        red[w * 4 + j][64 + c] = y > 0.f ? y : 0.01f * y;
    }
    if (c < 4) {
        int node = n0 + c;
        gid[w * 4 + c] = (node < GN_N) ? batch[node] : -1;
    }
    __syncthreads();
    if (w == 0) {
        int stripe = blockIdx.x & 31;
        int i = 0;
        while (i < 16) {
            int gg = gid[i];
            float s0 = 0.f, s1 = 0.f;
            int j = i;
            while (j < 16 && gid[j] == gg) { s0 += red[j][c]; s1 += red[j][64 + c]; ++j; }
            if (gg >= 0) {
                float* dstp = &sums[(size_t)(stripe * GN_G + gg) * 256 + c0 + c];
                atomicAdd(dstp, s0);
                atomicAdd(dstp + 64, s1);
            }
            i = j;
        }
    }
}

// One block per graph: reduce 32 stripes; Pl = sums[g]/cnt[g];
// Pg = Pl @ Wl3 + bl3; BN-MLP chain.
__global__ __launch_bounds__(256) void mlp_kernel(
    const float* __restrict__ sums, const float* __restrict__ cnt,
    const float* __restrict__ Wl3, const float* __restrict__ bl3,
    const float* __restrict__ W1, const float* __restrict__ b1,
    const float* __restrict__ Wh, const float* __restrict__ bh,
    const float* __restrict__ Wo, const float* __restrict__ bo,
    const float* __restrict__ gamma, const float* __restrict__ beta,
    const float* __restrict__ mean, const float* __restrict__ var,
    float* __restrict__ out)
{
    __shared__ float sp[256];
    __shared__ float pg[256];
    __shared__ float h0[64], h1[64];
    const int g = blockIdx.x;
    const int t = threadIdx.x;
    const float inv = 1.0f / fmaxf(cnt[g], 1.0f);

    {
        float acc = 0.f;
        #pragma unroll 8
        for (int st = 0; st < 32; ++st)
            acc += sums[(size_t)(st * GN_G + g) * 256 + t];
        sp[t] = acc * inv;
    }
    __syncthreads();

    {
        float a0 = 0.f, a1 = 0.f, a2 = 0.f, a3 = 0.f;
        #pragma unroll 4
        for (int k = 0; k < 256; k += 4) {
            a0 += sp[k + 0] * Wl3[(k + 0) * 256 + t];
            a1 += sp[k + 1] * Wl3[(k + 1) * 256 + t];
            a2 += sp[k + 2] * Wl3[(k + 2) * 256 + t];
            a3 += sp[k + 3] * Wl3[(k + 3) * 256 + t];
        }
        pg[t] = bl3[t] + ((a0 + a1) + (a2 + a3));
    }
    __syncthreads();

    if (t < 64) {
        float a0 = 0.f, a1 = 0.f, a2 = 0.f, a3 = 0.f;
        #pragma unroll 4
        for (int k = 0; k < 256; k += 4) {
            a0 += pg[k + 0] * W1[(k + 0) * 64 + t];
            a1 += pg[k + 1] * W1[(k + 1) * 64 + t];
            a2 += pg[k + 2] * W1[(k + 2) * 64 + t];
            a3 += pg[k + 3] * W1[(k + 3) * 64 + t];
        }
        float acc = b1[t] + ((a0 + a1) + (a2 + a3));
        float sc = gamma[t] * rsqrtf(var[t] + 1e-5f);
        acc = (acc - mean[t]) * sc + beta[t];
        h0[t] = fmaxf(acc, 0.0f);
    }
    __syncthreads();

    for (int L = 0; L < 3; ++L) {
        const float* W  = Wh + L * 64 * 64;
        const float* hin  = (L & 1) ? h1 : h0;
        float*       hout = (L & 1) ? h0 : h1;
        if (t < 64) {
            const float* ga = gamma + (L + 1) * 64;
            const float* be = beta  + (L + 1) * 64;
            const float* me = mean  + (L + 1) * 64;
            const float* va = var   + (L + 1) * 64;
            float a0 = 0.f, a1 = 0.f, a2 = 0.f, a3 = 0.f;
            #pragma unroll 4
            for (int k = 0; k < 64; k += 4) {
                a0 += hin[k + 0] * W[(k + 0) * 64 + t];
                a1 += hin[k + 1] * W[(k + 1) * 64 + t];
                a2 += hin[k + 2] * W[(k + 2) * 64 + t];
                a3 += hin[k + 3] * W[(k + 3) * 64 + t];
            }
            float acc = (bh + L * 64)[t] + ((a0 + a1) + (a2 + a3));
            float sc = ga[t] * rsqrtf(va[t] + 1e-5f);
            acc = (acc - me[t]) * sc + be[t];
            hout[t] = fmaxf(acc, 0.0f);
        }
        __syncthreads();
    }

    if (t < 8) {
        const float* hf = h1;
        float acc = bo[t];
        for (int k = 0; k < 64; ++k) acc += hf[k] * Wo[k * 8 + t];
        out[g * 8 + t] = acc;
    }
}

extern "C" void kernel_launch(void* const* d_in, const int* in_sizes, int n_in,
                              void* d_out, int out_size, void* d_ws, size_t ws_size,
                              hipStream_t stream)
{
    const int N = GN_N, E = GN_E;
    const float* x          = (const float*)d_in[0];
    const int*   edge_index = (const int*)d_in[1];
    const int*   batch      = (const int*)d_in[2];
    const int*   src = edge_index;
    const int*   dst = edge_index + E;
    auto F = [&](int i) { return (const float*)d_in[i]; };

    // ---- workspace layout ----
    float* ws    = (float*)d_ws;
    float* sums  = ws;                          // 32 stripes x 32 x 256
    float* cnt   = sums + 32 * GN_G * 256;      // 32
    float* bcat  = cnt + GN_G;                  // 1792
    ushort* Whi  = (ushort*)(bcat + 1792);
    ushort* Wlo  = Whi + W_TOTAL;
    ushort* xbf  = Wlo + W_TOTAL;               // N x 128 bf16
    ushort* hAbf = xbf + (size_t)N * 128;       // N x 64 bf16
    ushort* hBbf = hAbf + (size_t)N * 64;       // N x 128 bf16
    ushort* Gbf  = hBbf + (size_t)N * 128;      // N x 512 bf16
    ushort* Abf  = Gbf + (size_t)N * 512;       // N x 128 bf16 (pre-Wl acts)
    int* deg     = (int*)(Abf + (size_t)N * 128);
    int* cursor  = deg + N;
    int* row_ptr = cursor + N;                  // N+1
    int* elist   = row_ptr + (N + 1);           // E
    int* bsums   = elist + E;                   // 512
    int* se      = bsums + 512;                 // 64

    size_t need = (size_t)((char*)(se + 64) - (char*)ws);
    if (ws_size < need) return;

    // ---- CSR build + graph bounds ----
    const int eb = (E + 255) / 256;
    const int nb = (N + 255) / 256;
    zero_int<<<nb, 256, 0, stream>>>(deg, N);
    zero_int<<<1, 256, 0, stream>>>(se, 64);
    hist_kernel<<<eb, 256, 0, stream>>>(dst, deg);
    scan1<<<nb, 256, 0, stream>>>(deg, row_ptr, bsums);
    scan2<<<1, 512, 0, stream>>>(bsums, nb);
    scan3<<<nb, 256, 0, stream>>>(bsums, row_ptr, cursor);
    scatter_kernel<<<eb, 256, 0, stream>>>(src, dst, cursor, elist);
    bounds_kernel<<<nb, 256, 0, stream>>>(batch, se);
    cnt_kernel<<<1, 64, 0, stream>>>(se, cnt);

    // ---- weight + input pre-conversion (+ sums zeroing in aconv) ----
    WSrc S;
    for (int l = 0; l < 3; ++l) {
        int base = 3 + l * 10;
        for (int g = 0; g < 4; ++g) S.Wg[l][g] = F(base + g);
        for (int g = 0; g < 4; ++g) S.bg[l][g] = F(base + 4 + g);
    }
    S.Wl[0] = F(11); S.Wl[1] = F(21);
    wconv<<<(W_TOTAL + 1792 + 255) / 256, 256, 0, stream>>>(S, Whi, Wlo, bcat);
    aconv<<<(N * 16 + 255) / 256, 256, 0, stream>>>(x, xbf, sums);

    const int rb = (N + 127) / 128;
    const int gatherBlocks = (N + 15) / 16;

    // ---- layer 1 (256 cols: [K64|QV128|S64]) ----
    gemm2<128, 0><<<dim3(rb, 2), 512, 0, stream>>>(
        xbf, 128, Whi, Wlo, bcat, Gbf, 256, 128);
    edge_gather_w<<<gatherBlocks, 256, 0, stream>>>(Gbf, Abf, row_ptr, elist);
    gemm2<64, 2><<<dim3(rb, 1), 256, 0, stream>>>(
        Abf, 64, Whi + WOFF_WL1, Wlo + WOFF_WL1, F(12), hAbf, 64, 64);

    // ---- layer 2 (one 512-col group: [K128|QV256|S128]) ----
    gemm2<128, 0><<<dim3(rb, 4), 512, 0, stream>>>(
        hAbf, 64, Whi + WOFF_L2, Wlo + WOFF_L2, bcat + 256, Gbf, 512, 64);
    edge_gather_w2<<<gatherBlocks, 256, 0, stream>>>(Gbf, Abf, row_ptr, elist);
    gemm2<128, 2><<<dim3(rb, 1), 512, 0, stream>>>(
        Abf, 128, Whi + WOFF_WL2, Wlo + WOFF_WL2, F(22), hBbf, 128, 128);

    // ---- layer 3 (2 groups x 512 cols, fused pool) ----
    for (int ch = 0; ch < 2; ++ch) {
        size_t go = WOFF_L3 + (size_t)ch * 65536;
        gemm2<128, 0><<<dim3(rb, 4), 512, 0, stream>>>(
            hBbf, 128, Whi + go, Wlo + go, bcat + 768 + ch * 512, Gbf, 512, 128);
        edge_gather_pool2<<<gatherBlocks, 256, 0, stream>>>(
            Gbf, row_ptr, elist, batch, sums, ch * 128);
    }

    mlp_kernel<<<GN_G, 256, 0, stream>>>(sums, cnt, F(31), F(32),
                                         F(33), F(34), F(35), F(36), F(37), F(38),
                                         F(39), F(40), F(41), F(42),
                                         (float*)d_out);
}

// Round 5
// 642.046 us; speedup vs baseline: 1.1451x; 1.0259x over previous
//
#include <hip/hip_runtime.h>
#include <hip/hip_bf16.h>

// ---------------------------------------------------------------------------
// QuadraticGNN: 3x ResGatedGraphConv (ReLU gate, LeakyReLU 0.01, linear Wl)
//               -> global mean pool (32 graphs) -> 5-layer MLP with BN.
// Round 17:
//   - Wl GEMMs eliminated by weight composition: no nonlinearity sits
//     between Wl_l and layer l+1's gate GEMM, so
//       gates_{l+1} = leaky(h_pre) @ (Wl_l @ Wg_{l+1}) + (bl_l @ Wg + bg).
//     compose_l2 (64x512) and compose_l3 (128x1024) build the products in
//     fp32 on device and hi/lo-split; the gate gemms run AMODE=2 (leaky
//     at stage) straight from the gather outputs h1/h2. Wl3 was already
//     applied post-pool in mlp_kernel. Removes 2 gemm dispatches + the
//     hAbf/hBbf round trips (~77 MB), removes one bf16 rounding step.
//   - R16 structure otherwise unchanged (single-buffer gemm2 512-thread,
//     QV-interleaved Gbf, dual gathers, striped pool atomics).
// ---------------------------------------------------------------------------

#define GN_N 100000
#define GN_E 300000
#define GN_G 32

typedef __attribute__((ext_vector_type(8))) short short8;
typedef __attribute__((ext_vector_type(4))) float floatx4;

__device__ inline ushort f2bf_rne(float f) {
    unsigned u = __float_as_uint(f);
    unsigned r = u + 0x7fffu + ((u >> 16) & 1u);
    return (ushort)(r >> 16);
}
__device__ inline float bf2f(ushort h) { return __uint_as_float(((unsigned)h) << 16); }

// W-array layout (ushort offsets), k-major [col][K] per segment.
// L1: 256 cols x K128 [K64|QV128|S64].
// L2 (composed Wl1@Wg2): 512 cols x K64 [K128|QV256|S128].
// L3 (composed Wl2@Wg3): 2 groups x 512 cols x K128 [K128|QV256|S128].
#define WOFF_L2   32768
#define WOFF_L3   65536
#define W_TOTAL   196608

struct W1Src { const float* Wg[4]; const float* bg[4]; };
struct CSrc  { const float* Wl; const float* bl; const float* Wg[4]; const float* bg[4]; };

__global__ void wconv_l1(W1Src S, ushort* __restrict__ hi, ushort* __restrict__ lo,
                         float* __restrict__ biascat)
{
    int id = blockIdx.x * 256 + threadIdx.x;
    if (id < 32768) {
        int g  = id >> 13;          // 4 gates x (64 cols x 128 k)
        int r2 = id & 8191;
        int c  = r2 >> 7;
        int k  = r2 & 127;
        float v = S.Wg[g][k * 64 + c];
        int colIdx = (g == 0) ? c : (g == 3) ? (192 + c) : (64 + 2 * c + (g - 1));
        int dst = colIdx * 128 + k;
        ushort h = f2bf_rne(v);
        hi[dst] = h; lo[dst] = f2bf_rne(v - bf2f(h));
    } else if (id < 32768 + 256) {
        int p = id - 32768;
        int g, cc;
        if (p < 64)       { g = 0; cc = p; }
        else if (p < 192) { g = 1 + ((p - 64) & 1); cc = (p - 64) >> 1; }
        else              { g = 3; cc = p - 192; }
        biascat[p] = S.bg[g][cc];
    }
}

// W2' = Wl1(64x64) @ Wg2(64x128/gate): 512 packed cols x K=64.
__global__ void compose_l2(CSrc S, ushort* __restrict__ hi, ushort* __restrict__ lo,
                           float* __restrict__ biascat)
{
    int id = blockIdx.x * 256 + threadIdx.x;
    if (id >= 512 * 64) return;
    int p = id >> 6, k = id & 63;
    int g, cc;
    if (p < 128)      { g = 0; cc = p; }
    else if (p < 384) { g = 1 + ((p - 128) & 1); cc = (p - 128) >> 1; }
    else              { g = 3; cc = p - 384; }
    const float* wg = S.Wg[g];
    float acc = 0.f;
    #pragma unroll 8
    for (int j = 0; j < 64; ++j)
        acc += S.Wl[k * 64 + j] * wg[j * 128 + cc];
    int dst = WOFF_L2 + p * 64 + k;
    ushort h = f2bf_rne(acc);
    hi[dst] = h; lo[dst] = f2bf_rne(acc - bf2f(h));
    if (k == 0) {
        float b = S.bg[g][cc];
        #pragma unroll 8
        for (int j = 0; j < 64; ++j) b += S.bl[j] * wg[j * 128 + cc];
        biascat[256 + p] = b;
    }
}

// W3' = Wl2(128x128) @ Wg3(128x256/gate): 2 groups x 512 packed cols x K=128.
__global__ void compose_l3(CSrc S, ushort* __restrict__ hi, ushort* __restrict__ lo,
                           float* __restrict__ biascat)
{
    int id = blockIdx.x * 256 + threadIdx.x;
    if (id >= 1024 * 128) return;
    int p = id >> 7, k = id & 127;
    int ch = p >> 9, pp = p & 511;
    int g, cc;
    if (pp < 128)      { g = 0; cc = pp; }
    else if (pp < 384) { g = 1 + ((pp - 128) & 1); cc = (pp - 128) >> 1; }
    else               { g = 3; cc = pp - 384; }
    int srcc = ch * 128 + cc;
    const float* wg = S.Wg[g];
    float acc = 0.f;
    #pragma unroll 8
    for (int j = 0; j < 128; ++j)
        acc += S.Wl[k * 128 + j] * wg[j * 256 + srcc];
    int dst = WOFF_L3 + ch * 65536 + pp * 128 + k;
    ushort h = f2bf_rne(acc);
    hi[dst] = h; lo[dst] = f2bf_rne(acc - bf2f(h));
    if (k == 0) {
        float b = S.bg[g][srcc];
        #pragma unroll 8
        for (int j = 0; j < 128; ++j) b += S.bl[j] * wg[j * 256 + srcc];
        biascat[768 + ch * 512 + pp] = b;
    }
}

// x (fp32 [N][128]) -> bf16 [N][128]; also zeroes the striped pool sums.
__global__ void aconv(const float* __restrict__ A, ushort* __restrict__ O,
                      float* __restrict__ sums)
{
    int id = blockIdx.x * 256 + threadIdx.x;
    if (id < 32 * GN_G * 256) sums[id] = 0.0f;
    if (id >= GN_N * 16) return;
    int r = id >> 4, cc = id & 15;
    const float* src = A + (size_t)r * 128 + cc * 8;
    short8 h;
    #pragma unroll
    for (int j = 0; j < 8; ++j) h[j] = (short)f2bf_rne(src[j]);
    *(short8*)&O[(size_t)r * 128 + cc * 8] = h;
}

// GEMM: 128 rows x BC cols per block. A bf16; AMODE=0 copy-stage,
// AMODE=2 bf16 + leaky(0.01) stage. B hi/lo: 2 MFMAs per tile.
// Single-buffer LDS (R14 structure; dbuf regressed occupancy in R15).
template<int BC, int AMODE>
__global__ __launch_bounds__((BC == 128) ? 512 : 256, 4) void gemm2(
    const ushort* __restrict__ Aptr, int lda,
    const ushort* __restrict__ Bh, const ushort* __restrict__ Bl,
    const float* __restrict__ bias,
    ushort* __restrict__ Obf, int ldo,
    int K)
{
    constexpr int NT = (BC == 128) ? 512 : 256;
    constexpr int ST = 34;    // LDS row stride (ushorts): 17 words, odd
    __shared__ ushort sA[128 * ST];
    __shared__ ushort sBh[BC * ST], sBl[BC * ST];

    const int tid  = threadIdx.x;
    const int w    = tid >> 6, lane = tid & 63;
    const int m    = lane & 15, quad = lane >> 4;
    const int row0 = blockIdx.x * 128;
    const int col0 = blockIdx.y * BC;
    const int wr   = (BC == 128) ? (w >> 1) * 32 : w * 32;
    const int wc   = (BC == 128) ? (w & 1) * 64 : 0;

    floatx4 acc[2][4];
    #pragma unroll
    for (int i = 0; i < 2; ++i)
        #pragma unroll
        for (int j = 0; j < 4; ++j) acc[i][j] = (floatx4){0.f, 0.f, 0.f, 0.f};

    for (int k0 = 0; k0 < K; k0 += 32) {
        // ---- stage A ----
        if constexpr (NT == 512) {
            const int ar = tid >> 2, ak = (tid & 3) * 8;
            const int arow = row0 + ar;
            short8 a0;
            if (arow < GN_N) {
                const ushort* ap = Aptr + (size_t)arow * lda + k0 + ak;
                a0 = *(const short8*)ap;
                if constexpr (AMODE == 2) {
                    #pragma unroll
                    for (int j = 0; j < 8; ++j) {
                        float f = bf2f((ushort)a0[j]);
                        f = f > 0.f ? f : 0.01f * f;
                        a0[j] = (short)f2bf_rne(f);
                    }
                }
            } else {
                #pragma unroll
                for (int j = 0; j < 8; ++j) a0[j] = 0;
            }
            *(short8*)&sA[ar * ST + ak] = a0;
        } else {
            const int ar = tid >> 1, ak = (tid & 1) * 16;
            const int arow = row0 + ar;
            short8 a0, a1;
            if (arow < GN_N) {
                const ushort* ap = Aptr + (size_t)arow * lda + k0 + ak;
                a0 = *(const short8*)ap;
                a1 = *(const short8*)(ap + 8);
                if constexpr (AMODE == 2) {
                    #pragma unroll
                    for (int j = 0; j < 8; ++j) {
                        float f = bf2f((ushort)a0[j]); f = f > 0.f ? f : 0.01f * f;
                        a0[j] = (short)f2bf_rne(f);
                        float g = bf2f((ushort)a1[j]); g = g > 0.f ? g : 0.01f * g;
                        a1[j] = (short)f2bf_rne(g);
                    }
                }
            } else {
                #pragma unroll
                for (int j = 0; j < 8; ++j) { a0[j] = 0; a1[j] = 0; }
            }
            *(short8*)&sA[ar * ST + ak]     = a0;
            *(short8*)&sA[ar * ST + ak + 8] = a1;
        }
        // ---- stage B (NT/4 == BC in both instantiations) ----
        {
            const int col = tid >> 2, bk = (tid & 3) * 8;
            size_t off = (size_t)(col0 + col) * K + k0 + bk;
            *(short8*)&sBh[col * ST + bk] = *(const short8*)(Bh + off);
            *(short8*)&sBl[col * ST + bk] = *(const short8*)(Bl + off);
        }
        __syncthreads();
        // ---- compute: 2 MFMAs per tile ----
        short8 bhf[4], blf[4];
        #pragma unroll
        for (int ct = 0; ct < 4; ++ct) {
            bhf[ct] = *(const short8*)&sBh[(wc + ct * 16 + m) * ST + quad * 8];
            blf[ct] = *(const short8*)&sBl[(wc + ct * 16 + m) * ST + quad * 8];
        }
        #pragma unroll
        for (int rt = 0; rt < 2; ++rt) {
            short8 ahf = *(const short8*)&sA[(wr + rt * 16 + m) * ST + quad * 8];
            #pragma unroll
            for (int ct = 0; ct < 4; ++ct) {
                acc[rt][ct] = __builtin_amdgcn_mfma_f32_16x16x32_bf16(ahf, bhf[ct], acc[rt][ct], 0, 0, 0);
                acc[rt][ct] = __builtin_amdgcn_mfma_f32_16x16x32_bf16(ahf, blf[ct], acc[rt][ct], 0, 0, 0);
            }
        }
        __syncthreads();
    }

    #pragma unroll
    for (int rt = 0; rt < 2; ++rt) {
        #pragma unroll
        for (int ct = 0; ct < 4; ++ct) {
            int ocol = col0 + wc + ct * 16 + m;
            float bb = bias[ocol];
            #pragma unroll
            for (int reg = 0; reg < 4; ++reg) {
                int orow = row0 + wr + rt * 16 + quad * 4 + reg;
                if (orow >= GN_N) continue;
                Obf[(size_t)orow * ldo + ocol] = f2bf_rne(acc[rt][ct][reg] + bb);
            }
        }
    }
}

// ---------------- CSR build ----------------
__global__ void zero_int(int* p, int n)
{
    int i = blockIdx.x * 256 + threadIdx.x;
    if (i < n) p[i] = 0;
}

__global__ void hist_kernel(const int* __restrict__ dst, int* __restrict__ deg)
{
    int e = blockIdx.x * 256 + threadIdx.x;
    if (e < GN_E) atomicAdd(&deg[dst[e]], 1);
}

__global__ void scan1(const int* __restrict__ deg, int* __restrict__ rp, int* __restrict__ bsums)
{
    __shared__ int s[256];
    int b = blockIdx.x, t = threadIdx.x;
    int i = b * 256 + t;
    int v = (i < GN_N) ? deg[i] : 0;
    s[t] = v;
    __syncthreads();
    for (int off = 1; off < 256; off <<= 1) {
        int x = (t >= off) ? s[t - off] : 0;
        __syncthreads();
        s[t] += x;
        __syncthreads();
    }
    if (i < GN_N) rp[i] = s[t] - v;
    if (t == 255) bsums[b] = s[255];
}

__global__ __launch_bounds__(512) void scan2(int* bsums, int nb)
{
    __shared__ int s[512];
    int t = threadIdx.x;
    int v = (t < nb) ? bsums[t] : 0;
    s[t] = v;
    __syncthreads();
    for (int off = 1; off < 512; off <<= 1) {
        int x = (t >= off) ? s[t - off] : 0;
        __syncthreads();
        s[t] += x;
        __syncthreads();
    }
    if (t < nb) bsums[t] = s[t] - v;
}

__global__ void scan3(const int* __restrict__ bsums, int* __restrict__ rp, int* __restrict__ cursor)
{
    int b = blockIdx.x, t = threadIdx.x;
    int i = b * 256 + t;
    if (i < GN_N) {
        int v = rp[i] + bsums[b];
        rp[i] = v; cursor[i] = v;
    }
    if (i == 0) rp[GN_N] = GN_E;
}

__global__ void scatter_kernel(
    const int* __restrict__ src, const int* __restrict__ dst,
    int* __restrict__ cursor, int* __restrict__ elist)
{
    int e = blockIdx.x * 256 + threadIdx.x;
    if (e >= GN_E) return;
    int d = dst[e];
    int pos = atomicAdd(&cursor[d], 1);
    elist[pos] = src[e];
}

__global__ void bounds_kernel(const int* __restrict__ batch, int* __restrict__ se)
{
    int i = blockIdx.x * 256 + threadIdx.x;
    if (i >= GN_N) return;
    int g = batch[i];
    if (i == 0 || batch[i - 1] != g) se[g] = i;
    if (i == GN_N - 1 || batch[i + 1] != g) se[32 + g] = i + 1;
}

__global__ void cnt_kernel(const int* __restrict__ se, float* __restrict__ cnt)
{
    int g = threadIdx.x;
    if (g < GN_G) cnt[g] = (float)(se[32 + g] - se[g]);
}

// Layer-1 gather. Gbf row 256 = [K64|QV128|S64]. 4 nodes/wave, 8-edge batch.
// Writes h1 pre-acts bf16 [N][64].
__global__ __launch_bounds__(256, 2) void edge_gather_w(
    const ushort* __restrict__ Gbf, ushort* __restrict__ Abf,
    const int* __restrict__ row_ptr, const int* __restrict__ elist)
{
    int w = threadIdx.x >> 6, c = threadIdx.x & 63;
    int n0 = blockIdx.x * 16 + w * 4;

    float k[4], acc[4];
    int beg[4], end[4];
    #pragma unroll
    for (int j = 0; j < 4; ++j) {
        int node = n0 + j;
        bool ok = node < GN_N;
        int nd = ok ? node : 0;
        beg[j] = row_ptr[nd];
        end[j] = ok ? row_ptr[nd + 1] : beg[j];
        k[j]   = bf2f(Gbf[(size_t)nd * 256 + c]);
        acc[j] = bf2f(Gbf[(size_t)nd * 256 + 192 + c]);
    }
    int s[32];
    #pragma unroll
    for (int j = 0; j < 4; ++j) {
        #pragma unroll
        for (int e = 0; e < 8; ++e) {
            int idx = beg[j] + e;
            s[j * 8 + e] = elist[idx < end[j] ? idx : 0];
        }
    }
    uint qv[32];
    #pragma unroll
    for (int je = 0; je < 32; ++je)
        qv[je] = *(const uint*)&Gbf[(size_t)s[je] * 256 + 64 + 2 * c];
    #pragma unroll
    for (int j = 0; j < 4; ++j) {
        #pragma unroll
        for (int e = 0; e < 8; ++e) {
            if (beg[j] + e < end[j]) {
                uint p = qv[j * 8 + e];
                float gt = k[j] + bf2f((ushort)(p & 0xffffu));
                if (gt > 0.f) acc[j] += gt * bf2f((ushort)(p >> 16));
            }
        }
    }
    #pragma unroll
    for (int j = 0; j < 4; ++j) {
        for (int i = beg[j] + 8; i < end[j]; ++i) {
            int ss = elist[i];
            uint p = *(const uint*)&Gbf[(size_t)ss * 256 + 64 + 2 * c];
            float gt = k[j] + bf2f((ushort)(p & 0xffffu));
            if (gt > 0.f) acc[j] += gt * bf2f((ushort)(p >> 16));
        }
    }
    #pragma unroll
    for (int j = 0; j < 4; ++j)
        if (n0 + j < GN_N) Abf[(size_t)(n0 + j) * 64 + c] = f2bf_rne(acc[j]);
}

// Layer-2 dual gather. Gbf row 512 = [K128|QV256|S128]; thread handles
// channels c and 64+c. Writes h2 pre-acts bf16 [N][128].
__global__ __launch_bounds__(256, 2) void edge_gather_w2(
    const ushort* __restrict__ Gbf, ushort* __restrict__ Abf,
    const int* __restrict__ row_ptr, const int* __restrict__ elist)
{
    int w = threadIdx.x >> 6, c = threadIdx.x & 63;
    int n0 = blockIdx.x * 16 + w * 4;

    float k0[4], k1[4], a0[4], a1[4];
    int beg[4], end[4];
    #pragma unroll
    for (int j = 0; j < 4; ++j) {
        int node = n0 + j;
        bool ok = node < GN_N;
        int nd = ok ? node : 0;
        beg[j] = row_ptr[nd];
        end[j] = ok ? row_ptr[nd + 1] : beg[j];
        size_t b = (size_t)nd * 512;
        k0[j] = bf2f(Gbf[b + c]);
        k1[j] = bf2f(Gbf[b + 64 + c]);
        a0[j] = bf2f(Gbf[b + 384 + c]);
        a1[j] = bf2f(Gbf[b + 448 + c]);
    }
    int s[32];
    #pragma unroll
    for (int j = 0; j < 4; ++j) {
        #pragma unroll
        for (int e = 0; e < 8; ++e) {
            int idx = beg[j] + e;
            s[j * 8 + e] = elist[idx < end[j] ? idx : 0];
        }
    }
    uint qv0[32], qv1[32];
    #pragma unroll
    for (int je = 0; je < 32; ++je) {
        size_t b = (size_t)s[je] * 512;
        qv0[je] = *(const uint*)&Gbf[b + 128 + 2 * c];
        qv1[je] = *(const uint*)&Gbf[b + 256 + 2 * c];
    }
    #pragma unroll
    for (int j = 0; j < 4; ++j) {
        #pragma unroll
        for (int e = 0; e < 8; ++e) {
            if (beg[j] + e < end[j]) {
                uint p = qv0[j * 8 + e];
                float gt = k0[j] + bf2f((ushort)(p & 0xffffu));
                if (gt > 0.f) a0[j] += gt * bf2f((ushort)(p >> 16));
                uint q = qv1[j * 8 + e];
                float gu = k1[j] + bf2f((ushort)(q & 0xffffu));
                if (gu > 0.f) a1[j] += gu * bf2f((ushort)(q >> 16));
            }
        }
    }
    #pragma unroll
    for (int j = 0; j < 4; ++j) {
        for (int i = beg[j] + 8; i < end[j]; ++i) {
            size_t b = (size_t)elist[i] * 512;
            uint p = *(const uint*)&Gbf[b + 128 + 2 * c];
            uint q = *(const uint*)&Gbf[b + 256 + 2 * c];
            float gt = k0[j] + bf2f((ushort)(p & 0xffffu));
            if (gt > 0.f) a0[j] += gt * bf2f((ushort)(p >> 16));
            float gu = k1[j] + bf2f((ushort)(q & 0xffffu));
            if (gu > 0.f) a1[j] += gu * bf2f((ushort)(q >> 16));
        }
    }
    #pragma unroll
    for (int j = 0; j < 4; ++j)
        if (n0 + j < GN_N) {
            Abf[(size_t)(n0 + j) * 128 + c]      = f2bf_rne(a0[j]);
            Abf[(size_t)(n0 + j) * 128 + 64 + c] = f2bf_rne(a1[j]);
        }
}

// Layer-3 dual gather + leaky + pool. Gbf row 512; channels c0+c, c0+64+c.
__global__ __launch_bounds__(256, 2) void edge_gather_pool2(
    const ushort* __restrict__ Gbf,
    const int* __restrict__ row_ptr, const int* __restrict__ elist,
    const int* __restrict__ batch,
    float* __restrict__ sums, int c0)
{
    __shared__ float red[16][128];
    __shared__ int gid[16];
    int w = threadIdx.x >> 6, c = threadIdx.x & 63;
    int n0 = blockIdx.x * 16 + w * 4;

    float k0[4], k1[4], a0[4], a1[4];
    int beg[4], end[4];
    #pragma unroll
    for (int j = 0; j < 4; ++j) {
        int node = n0 + j;
        bool ok = node < GN_N;
        int nd = ok ? node : 0;
        beg[j] = row_ptr[nd];
        end[j] = ok ? row_ptr[nd + 1] : beg[j];
        size_t b = (size_t)nd * 512;
        k0[j] = bf2f(Gbf[b + c]);
        k1[j] = bf2f(Gbf[b + 64 + c]);
        a0[j] = ok ? bf2f(Gbf[b + 384 + c]) : 0.f;
        a1[j] = ok ? bf2f(Gbf[b + 448 + c]) : 0.f;
    }
    int s[32];
    #pragma unroll
    for (int j = 0; j < 4; ++j) {
        #pragma unroll
        for (int e = 0; e < 8; ++e) {
            int idx = beg[j] + e;
            s[j * 8 + e] = elist[idx < end[j] ? idx : 0];
        }
    }
    uint qv0[32], qv1[32];
    #pragma unroll
    for (int je = 0; je < 32; ++je) {
        size_t b = (size_t)s[je] * 512;
        qv0[je] = *(const uint*)&Gbf[b + 128 + 2 * c];
        qv1[je] = *(const uint*)&Gbf[b + 256 + 2 * c];
    }
    #pragma unroll
    for (int j = 0; j < 4; ++j) {
        #pragma unroll
        for (int e = 0; e < 8; ++e) {
            if (beg[j] + e < end[j]) {
                uint p = qv0[j * 8 + e];
                float gt = k0[j] + bf2f((ushort)(p & 0xffffu));
                if (gt > 0.f) a0[j] += gt * bf2f((ushort)(p >> 16));
                uint q = qv1[j * 8 + e];
                float gu = k1[j] + bf2f((ushort)(q & 0xffffu));
                if (gu > 0.f) a1[j] += gu * bf2f((ushort)(q >> 16));
            }
        }
    }
    #pragma unroll
    for (int j = 0; j < 4; ++j) {
        for (int i = beg[j] + 8; i < end[j]; ++i) {
            size_t b = (size_t)elist[i] * 512;
            uint p = *(const uint*)&Gbf[b + 128 + 2 * c];
            uint q = *(const uint*)&Gbf[b + 256 + 2 * c];
            float gt = k0[j] + bf2f((ushort)(p & 0xffffu));
            if (gt > 0.f) a0[j] += gt * bf2f((ushort)(p >> 16));
            float gu = k1[j] + bf2f((ushort)(q & 0xffffu));
            if (gu > 0.f) a1[j] += gu * bf2f((ushort)(q >> 16));
        }
    }
    #pragma unroll
    for (int j = 0; j < 4; ++j) {
        float x = a0[j], y = a1[j];
        red[w * 4 + j][c]      = x > 0.f ? x : 0.01f * x;
        red[w * 4 + j][64 + c] = y > 0.f ? y : 0.01f * y;
    }
    if (c < 4) {
        int node = n0 + c;
        gid[w * 4 + c] = (node < GN_N) ? batch[node] : -1;
    }
    __syncthreads();
    if (w == 0) {
        int stripe = blockIdx.x & 31;
        int i = 0;
        while (i < 16) {
            int gg = gid[i];
            float s0 = 0.f, s1 = 0.f;
            int j = i;
            while (j < 16 && gid[j] == gg) { s0 += red[j][c]; s1 += red[j][64 + c]; ++j; }
            if (gg >= 0) {
                float* dstp = &sums[(size_t)(stripe * GN_G + gg) * 256 + c0 + c];
                atomicAdd(dstp, s0);
                atomicAdd(dstp + 64, s1);
            }
            i = j;
        }
    }
}

// One block per graph: reduce 32 stripes; Pl = sums[g]/cnt[g];
// Pg = Pl @ Wl3 + bl3; BN-MLP chain.
__global__ __launch_bounds__(256) void mlp_kernel(
    const float* __restrict__ sums, const float* __restrict__ cnt,
    const float* __restrict__ Wl3, const float* __restrict__ bl3,
    const float* __restrict__ W1, const float* __restrict__ b1,
    const float* __restrict__ Wh, const float* __restrict__ bh,
    const float* __restrict__ Wo, const float* __restrict__ bo,
    const float* __restrict__ gamma, const float* __restrict__ beta,
    const float* __restrict__ mean, const float* __restrict__ var,
    float* __restrict__ out)
{
    __shared__ float sp[256];
    __shared__ float pg[256];
    __shared__ float h0[64], h1[64];
    const int g = blockIdx.x;
    const int t = threadIdx.x;
    const float inv = 1.0f / fmaxf(cnt[g], 1.0f);

    {
        float acc = 0.f;
        #pragma unroll 8
        for (int st = 0; st < 32; ++st)
            acc += sums[(size_t)(st * GN_G + g) * 256 + t];
        sp[t] = acc * inv;
    }
    __syncthreads();

    {
        float a0 = 0.f, a1 = 0.f, a2 = 0.f, a3 = 0.f;
        #pragma unroll 4
        for (int k = 0; k < 256; k += 4) {
            a0 += sp[k + 0] * Wl3[(k + 0) * 256 + t];
            a1 += sp[k + 1] * Wl3[(k + 1) * 256 + t];
            a2 += sp[k + 2] * Wl3[(k + 2) * 256 + t];
            a3 += sp[k + 3] * Wl3[(k + 3) * 256 + t];
        }
        pg[t] = bl3[t] + ((a0 + a1) + (a2 + a3));
    }
    __syncthreads();

    if (t < 64) {
        float a0 = 0.f, a1 = 0.f, a2 = 0.f, a3 = 0.f;
        #pragma unroll 4
        for (int k = 0; k < 256; k += 4) {
            a0 += pg[k + 0] * W1[(k + 0) * 64 + t];
            a1 += pg[k + 1] * W1[(k + 1) * 64 + t];
            a2 += pg[k + 2] * W1[(k + 2) * 64 + t];
            a3 += pg[k + 3] * W1[(k + 3) * 64 + t];
        }
        float acc = b1[t] + ((a0 + a1) + (a2 + a3));
        float sc = gamma[t] * rsqrtf(var[t] + 1e-5f);
        acc = (acc - mean[t]) * sc + beta[t];
        h0[t] = fmaxf(acc, 0.0f);
    }
    __syncthreads();

    for (int L = 0; L < 3; ++L) {
        const float* W  = Wh + L * 64 * 64;
        const float* hin  = (L & 1) ? h1 : h0;
        float*       hout = (L & 1) ? h0 : h1;
        if (t < 64) {
            const float* ga = gamma + (L + 1) * 64;
            const float* be = beta  + (L + 1) * 64;
            const float* me = mean  + (L + 1) * 64;
            const float* va = var   + (L + 1) * 64;
            float a0 = 0.f, a1 = 0.f, a2 = 0.f, a3 = 0.f;
            #pragma unroll 4
            for (int k = 0; k < 64; k += 4) {
                a0 += hin[k + 0] * W[(k + 0) * 64 + t];
                a1 += hin[k + 1] * W[(k + 1) * 64 + t];
                a2 += hin[k + 2] * W[(k + 2) * 64 + t];
                a3 += hin[k + 3] * W[(k + 3) * 64 + t];
            }
            float acc = (bh + L * 64)[t] + ((a0 + a1) + (a2 + a3));
            float sc = ga[t] * rsqrtf(va[t] + 1e-5f);
            acc = (acc - me[t]) * sc + be[t];
            hout[t] = fmaxf(acc, 0.0f);
        }
        __syncthreads();
    }

    if (t < 8) {
        const float* hf = h1;
        float acc = bo[t];
        for (int k = 0; k < 64; ++k) acc += hf[k] * Wo[k * 8 + t];
        out[g * 8 + t] = acc;
    }
}

extern "C" void kernel_launch(void* const* d_in, const int* in_sizes, int n_in,
                              void* d_out, int out_size, void* d_ws, size_t ws_size,
                              hipStream_t stream)
{
    const int N = GN_N, E = GN_E;
    const float* x          = (const float*)d_in[0];
    const int*   edge_index = (const int*)d_in[1];
    const int*   batch      = (const int*)d_in[2];
    const int*   src = edge_index;
    const int*   dst = edge_index + E;
    auto F = [&](int i) { return (const float*)d_in[i]; };

    // ---- workspace layout ----
    float* ws    = (float*)d_ws;
    float* sums  = ws;                          // 32 stripes x 32 x 256
    float* cnt   = sums + 32 * GN_G * 256;      // 32
    float* bcat  = cnt + GN_G;                  // 1792
    ushort* Whi  = (ushort*)(bcat + 1792);
    ushort* Wlo  = Whi + W_TOTAL;
    ushort* xbf  = Wlo + W_TOTAL;               // N x 128 bf16
    ushort* h1bf = xbf + (size_t)N * 128;       // N x 64 bf16 (pre-acts)
    ushort* h2bf = h1bf + (size_t)N * 64;       // N x 128 bf16 (pre-acts)
    ushort* Gbf  = h2bf + (size_t)N * 128;      // N x 512 bf16
    int* deg     = (int*)(Gbf + (size_t)N * 512);
    int* cursor  = deg + N;
    int* row_ptr = cursor + N;                  // N+1
    int* elist   = row_ptr + (N + 1);           // E
    int* bsums   = elist + E;                   // 512
    int* se      = bsums + 512;                 // 64

    size_t need = (size_t)((char*)(se + 64) - (char*)ws);
    if (ws_size < need) return;

    // ---- CSR build + graph bounds ----
    const int eb = (E + 255) / 256;
    const int nb = (N + 255) / 256;
    zero_int<<<nb, 256, 0, stream>>>(deg, N);
    zero_int<<<1, 256, 0, stream>>>(se, 64);
    hist_kernel<<<eb, 256, 0, stream>>>(dst, deg);
    scan1<<<nb, 256, 0, stream>>>(deg, row_ptr, bsums);
    scan2<<<1, 512, 0, stream>>>(bsums, nb);
    scan3<<<nb, 256, 0, stream>>>(bsums, row_ptr, cursor);
    scatter_kernel<<<eb, 256, 0, stream>>>(src, dst, cursor, elist);
    bounds_kernel<<<nb, 256, 0, stream>>>(batch, se);
    cnt_kernel<<<1, 64, 0, stream>>>(se, cnt);

    // ---- weight prep: L1 pack; L2/L3 composed with previous Wl ----
    W1Src S1;
    for (int g = 0; g < 4; ++g) { S1.Wg[g] = F(3 + g); S1.bg[g] = F(7 + g); }
    wconv_l1<<<(32768 + 256 + 255) / 256, 256, 0, stream>>>(S1, Whi, Wlo, bcat);

    CSrc S2;
    S2.Wl = F(11); S2.bl = F(12);
    for (int g = 0; g < 4; ++g) { S2.Wg[g] = F(13 + g); S2.bg[g] = F(17 + g); }
    compose_l2<<<(512 * 64 + 255) / 256, 256, 0, stream>>>(S2, Whi, Wlo, bcat);

    CSrc S3;
    S3.Wl = F(21); S3.bl = F(22);
    for (int g = 0; g < 4; ++g) { S3.Wg[g] = F(23 + g); S3.bg[g] = F(27 + g); }
    compose_l3<<<(1024 * 128 + 255) / 256, 256, 0, stream>>>(S3, Whi, Wlo, bcat);

    aconv<<<(N * 16 + 255) / 256, 256, 0, stream>>>(x, xbf, sums);

    const int rb = (N + 127) / 128;
    const int gatherBlocks = (N + 15) / 16;

    // ---- layer 1 (256 cols: [K64|QV128|S64]) ----
    gemm2<128, 0><<<dim3(rb, 2), 512, 0, stream>>>(
        xbf, 128, Whi, Wlo, bcat, Gbf, 256, 128);
    edge_gather_w<<<gatherBlocks, 256, 0, stream>>>(Gbf, h1bf, row_ptr, elist);

    // ---- layer 2 (composed: leaky(h1) @ Wl1Wg2; 512 cols, K=64) ----
    gemm2<128, 2><<<dim3(rb, 4), 512, 0, stream>>>(
        h1bf, 64, Whi + WOFF_L2, Wlo + WOFF_L2, bcat + 256, Gbf, 512, 64);
    edge_gather_w2<<<gatherBlocks, 256, 0, stream>>>(Gbf, h2bf, row_ptr, elist);

    // ---- layer 3 (composed: leaky(h2) @ Wl2Wg3; 2 groups x 512, K=128) ----
    for (int ch = 0; ch < 2; ++ch) {
        size_t go = WOFF_L3 + (size_t)ch * 65536;
        gemm2<128, 2><<<dim3(rb, 4), 512, 0, stream>>>(
            h2bf, 128, Whi + go, Wlo + go, bcat + 768 + ch * 512, Gbf, 512, 128);
        edge_gather_pool2<<<gatherBlocks, 256, 0, stream>>>(
            Gbf, row_ptr, elist, batch, sums, ch * 128);
    }

    mlp_kernel<<<GN_G, 256, 0, stream>>>(sums, cnt, F(31), F(32),
                                         F(33), F(34), F(35), F(36), F(37), F(38),
                                         F(39), F(40), F(41), F(42),
                                         (float*)d_out);
}

// Round 7
// 631.058 us; speedup vs baseline: 1.1651x; 1.0174x over previous
//
#include <hip/hip_runtime.h>
#include <hip/hip_bf16.h>

// ---------------------------------------------------------------------------
// QuadraticGNN: 3x ResGatedGraphConv (ReLU gate, LeakyReLU 0.01, linear Wl)
//               -> global mean pool (32 graphs) -> 5-layer MLP with BN.
// Round 19 (= R18 resubmit with OOB fix):
//   - R18 never ran (container failed twice). Only new fault vector vs the
//     green R17 build was unguarded A-row DMA reads past N in gemm2's
//     global_load_lds staging. Rows >= N now clamp to row 0 (their outputs
//     are never written, so this is observationally identical but provably
//     in-bounds).
//   - gemm2: global_load_lds(16B) staging, linear LDS double-buffer,
//     pre-swizzled per-lane source addrs (store kc^((sub>>1)&3)), read-side
//     same XOR; one __syncthreads per K-step; grid(ncb, rb) col-fast.
//   - leaky lives in the gathers; all gemms pure-copy staging.
// ---------------------------------------------------------------------------

#define GN_N 100000
#define GN_E 300000
#define GN_G 32

typedef __attribute__((ext_vector_type(8))) short short8;
typedef __attribute__((ext_vector_type(4))) float floatx4;

__device__ inline ushort f2bf_rne(float f) {
    unsigned u = __float_as_uint(f);
    unsigned r = u + 0x7fffu + ((u >> 16) & 1u);
    return (ushort)(r >> 16);
}
__device__ inline float bf2f(ushort h) { return __uint_as_float(((unsigned)h) << 16); }

// W-array layout (ushort offsets), k-major [col][K] per segment.
// L1: 256 cols x K128 [K64|QV128|S64].
// L2 (composed Wl1@Wg2): 512 cols x K64 [K128|QV256|S128].
// L3 (composed Wl2@Wg3): 2 groups x 512 cols x K128 [K128|QV256|S128].
#define WOFF_L2   32768
#define WOFF_L3   65536
#define W_TOTAL   196608

struct W1Src { const float* Wg[4]; const float* bg[4]; };
struct CSrc  { const float* Wl; const float* bl; const float* Wg[4]; const float* bg[4]; };

__global__ void wconv_l1(W1Src S, ushort* __restrict__ hi, ushort* __restrict__ lo,
                         float* __restrict__ biascat)
{
    int id = blockIdx.x * 256 + threadIdx.x;
    if (id < 32768) {
        int g  = id >> 13;          // 4 gates x (64 cols x 128 k)
        int r2 = id & 8191;
        int c  = r2 >> 7;
        int k  = r2 & 127;
        float v = S.Wg[g][k * 64 + c];
        int colIdx = (g == 0) ? c : (g == 3) ? (192 + c) : (64 + 2 * c + (g - 1));
        int dst = colIdx * 128 + k;
        ushort h = f2bf_rne(v);
        hi[dst] = h; lo[dst] = f2bf_rne(v - bf2f(h));
    } else if (id < 32768 + 256) {
        int p = id - 32768;
        int g, cc;
        if (p < 64)       { g = 0; cc = p; }
        else if (p < 192) { g = 1 + ((p - 64) & 1); cc = (p - 64) >> 1; }
        else              { g = 3; cc = p - 192; }
        biascat[p] = S.bg[g][cc];
    }
}

// W2' = Wl1(64x64) @ Wg2(64x128/gate): 512 packed cols x K=64.
__global__ void compose_l2(CSrc S, ushort* __restrict__ hi, ushort* __restrict__ lo,
                           float* __restrict__ biascat)
{
    int id = blockIdx.x * 256 + threadIdx.x;
    if (id >= 512 * 64) return;
    int p = id >> 6, k = id & 63;
    int g, cc;
    if (p < 128)      { g = 0; cc = p; }
    else if (p < 384) { g = 1 + ((p - 128) & 1); cc = (p - 128) >> 1; }
    else              { g = 3; cc = p - 384; }
    const float* wg = S.Wg[g];
    float acc = 0.f;
    #pragma unroll 8
    for (int j = 0; j < 64; ++j)
        acc += S.Wl[k * 64 + j] * wg[j * 128 + cc];
    int dst = WOFF_L2 + p * 64 + k;
    ushort h = f2bf_rne(acc);
    hi[dst] = h; lo[dst] = f2bf_rne(acc - bf2f(h));
    if (k == 0) {
        float b = S.bg[g][cc];
        #pragma unroll 8
        for (int j = 0; j < 64; ++j) b += S.bl[j] * wg[j * 128 + cc];
        biascat[256 + p] = b;
    }
}

// W3' = Wl2(128x128) @ Wg3(128x256/gate): 2 groups x 512 packed cols x K=128.
__global__ void compose_l3(CSrc S, ushort* __restrict__ hi, ushort* __restrict__ lo,
                           float* __restrict__ biascat)
{
    int id = blockIdx.x * 256 + threadIdx.x;
    if (id >= 1024 * 128) return;
    int p = id >> 7, k = id & 127;
    int ch = p >> 9, pp = p & 511;
    int g, cc;
    if (pp < 128)      { g = 0; cc = pp; }
    else if (pp < 384) { g = 1 + ((pp - 128) & 1); cc = (pp - 128) >> 1; }
    else               { g = 3; cc = pp - 384; }
    int srcc = ch * 128 + cc;
    const float* wg = S.Wg[g];
    float acc = 0.f;
    #pragma unroll 8
    for (int j = 0; j < 128; ++j)
        acc += S.Wl[k * 128 + j] * wg[j * 256 + srcc];
    int dst = WOFF_L3 + ch * 65536 + pp * 128 + k;
    ushort h = f2bf_rne(acc);
    hi[dst] = h; lo[dst] = f2bf_rne(acc - bf2f(h));
    if (k == 0) {
        float b = S.bg[g][srcc];
        #pragma unroll 8
        for (int j = 0; j < 128; ++j) b += S.bl[j] * wg[j * 256 + srcc];
        biascat[768 + ch * 512 + pp] = b;
    }
}

// x (fp32 [N][128]) -> bf16 [N][128]; also zeroes the striped pool sums.
__global__ void aconv(const float* __restrict__ A, ushort* __restrict__ O,
                      float* __restrict__ sums)
{
    int id = blockIdx.x * 256 + threadIdx.x;
    if (id < 32 * GN_G * 256) sums[id] = 0.0f;
    if (id >= GN_N * 16) return;
    int r = id >> 4, cc = id & 15;
    const float* src = A + (size_t)r * 128 + cc * 8;
    short8 h;
    #pragma unroll
    for (int j = 0; j < 8; ++j) h[j] = (short)f2bf_rne(src[j]);
    *(short8*)&O[(size_t)r * 128 + cc * 8] = h;
}

// GEMM: 128 rows x 128 cols per block, 512 threads / 8 waves, pure-copy A.
// global_load_lds(16B) staging into linear LDS double-buffer; per-lane
// source addresses pre-swizzled so reads (same XOR) are bank-balanced.
// Grid (ncb, rb): col-fast dispatch so co-resident blocks share A.
__global__ __launch_bounds__(512) void gemm2(
    const ushort* __restrict__ Aptr, int lda,
    const ushort* __restrict__ Bh, const ushort* __restrict__ Bl,
    const float* __restrict__ bias,
    ushort* __restrict__ Obf, int ldo,
    int K)
{
    __shared__ ushort sA[2][128 * 32];
    __shared__ ushort sBh[2][128 * 32], sBl[2][128 * 32];

    const int tid  = threadIdx.x;
    const int w    = tid >> 6, lane = tid & 63;
    const int m    = lane & 15, quad = lane >> 4;
    const int row0 = blockIdx.y * 128;
    const int col0 = blockIdx.x * 128;
    const int wr   = (w >> 1) * 32;
    const int wc   = (w & 1) * 64;

    // staging: wave w covers rows/cols w*16..w*16+15; lane -> (sub, kc).
    // LDS unit u = (w*16+sub)*4 + kc holds data chunk kc^((sub>>1)&3).
    const int sub = lane >> 2;
    const int kc  = lane & 3;
    const int kcs = kc ^ ((sub >> 1) & 3);
    const int arow = row0 + w * 16 + sub;
    const int arowc = arow < GN_N ? arow : 0;   // clamp: in-bounds DMA source
    const ushort* aSrc  = Aptr + (size_t)arowc * lda + kcs * 8;
    const ushort* bhSrc = Bh   + (size_t)(col0 + w * 16 + sub) * K + kcs * 8;
    const ushort* blSrc = Bl   + (size_t)(col0 + w * 16 + sub) * K + kcs * 8;

    floatx4 acc[2][4];
    #pragma unroll
    for (int i = 0; i < 2; ++i)
        #pragma unroll
        for (int j = 0; j < 4; ++j) acc[i][j] = (floatx4){0.f, 0.f, 0.f, 0.f};

    auto stage = [&](int buf, int k0) {
        __builtin_amdgcn_global_load_lds(
            (const __attribute__((address_space(1))) void*)(aSrc + k0),
            (__attribute__((address_space(3))) void*)&sA[buf][w * 512], 16, 0, 0);
        __builtin_amdgcn_global_load_lds(
            (const __attribute__((address_space(1))) void*)(bhSrc + k0),
            (__attribute__((address_space(3))) void*)&sBh[buf][w * 512], 16, 0, 0);
        __builtin_amdgcn_global_load_lds(
            (const __attribute__((address_space(1))) void*)(blSrc + k0),
            (__attribute__((address_space(3))) void*)&sBl[buf][w * 512], 16, 0, 0);
    };

    const int nt = K >> 5;
    stage(0, 0);
    __syncthreads();

    const int rsw = (quad ^ ((m >> 1) & 3)) * 8;   // read-side swizzle (ushorts)
    int cur = 0;
    for (int t = 0; t < nt; ++t) {
        if (t + 1 < nt) stage(cur ^ 1, (t + 1) << 5);
        short8 bhf[4], blf[4];
        #pragma unroll
        for (int ct = 0; ct < 4; ++ct) {
            bhf[ct] = *(const short8*)&sBh[cur][(wc + ct * 16 + m) * 32 + rsw];
            blf[ct] = *(const short8*)&sBl[cur][(wc + ct * 16 + m) * 32 + rsw];
        }
        #pragma unroll
        for (int rt = 0; rt < 2; ++rt) {
            short8 ahf = *(const short8*)&sA[cur][(wr + rt * 16 + m) * 32 + rsw];
            #pragma unroll
            for (int ct = 0; ct < 4; ++ct) {
                acc[rt][ct] = __builtin_amdgcn_mfma_f32_16x16x32_bf16(ahf, bhf[ct], acc[rt][ct], 0, 0, 0);
                acc[rt][ct] = __builtin_amdgcn_mfma_f32_16x16x32_bf16(ahf, blf[ct], acc[rt][ct], 0, 0, 0);
            }
        }
        __syncthreads();
        cur ^= 1;
    }

    #pragma unroll
    for (int rt = 0; rt < 2; ++rt) {
        #pragma unroll
        for (int ct = 0; ct < 4; ++ct) {
            int ocol = col0 + wc + ct * 16 + m;
            float bb = bias[ocol];
            #pragma unroll
            for (int reg = 0; reg < 4; ++reg) {
                int orow = row0 + wr + rt * 16 + quad * 4 + reg;
                if (orow >= GN_N) continue;
                Obf[(size_t)orow * ldo + ocol] = f2bf_rne(acc[rt][ct][reg] + bb);
            }
        }
    }
}

// ---------------- CSR build ----------------
__global__ void zero_int(int* p, int n)
{
    int i = blockIdx.x * 256 + threadIdx.x;
    if (i < n) p[i] = 0;
}

__global__ void hist_kernel(const int* __restrict__ dst, int* __restrict__ deg)
{
    int e = blockIdx.x * 256 + threadIdx.x;
    if (e < GN_E) atomicAdd(&deg[dst[e]], 1);
}

__global__ void scan1(const int* __restrict__ deg, int* __restrict__ rp, int* __restrict__ bsums)
{
    __shared__ int s[256];
    int b = blockIdx.x, t = threadIdx.x;
    int i = b * 256 + t;
    int v = (i < GN_N) ? deg[i] : 0;
    s[t] = v;
    __syncthreads();
    for (int off = 1; off < 256; off <<= 1) {
        int x = (t >= off) ? s[t - off] : 0;
        __syncthreads();
        s[t] += x;
        __syncthreads();
    }
    if (i < GN_N) rp[i] = s[t] - v;
    if (t == 255) bsums[b] = s[255];
}

__global__ __launch_bounds__(512) void scan2(int* bsums, int nb)
{
    __shared__ int s[512];
    int t = threadIdx.x;
    int v = (t < nb) ? bsums[t] : 0;
    s[t] = v;
    __syncthreads();
    for (int off = 1; off < 512; off <<= 1) {
        int x = (t >= off) ? s[t - off] : 0;
        __syncthreads();
        s[t] += x;
        __syncthreads();
    }
    if (t < nb) bsums[t] = s[t] - v;
}

__global__ void scan3(const int* __restrict__ bsums, int* __restrict__ rp, int* __restrict__ cursor)
{
    int b = blockIdx.x, t = threadIdx.x;
    int i = b * 256 + t;
    if (i < GN_N) {
        int v = rp[i] + bsums[b];
        rp[i] = v; cursor[i] = v;
    }
    if (i == 0) rp[GN_N] = GN_E;
}

__global__ void scatter_kernel(
    const int* __restrict__ src, const int* __restrict__ dst,
    int* __restrict__ cursor, int* __restrict__ elist)
{
    int e = blockIdx.x * 256 + threadIdx.x;
    if (e >= GN_E) return;
    int d = dst[e];
    int pos = atomicAdd(&cursor[d], 1);
    elist[pos] = src[e];
}

__global__ void bounds_kernel(const int* __restrict__ batch, int* __restrict__ se)
{
    int i = blockIdx.x * 256 + threadIdx.x;
    if (i >= GN_N) return;
    int g = batch[i];
    if (i == 0 || batch[i - 1] != g) se[g] = i;
    if (i == GN_N - 1 || batch[i + 1] != g) se[32 + g] = i + 1;
}

__global__ void cnt_kernel(const int* __restrict__ se, float* __restrict__ cnt)
{
    int g = threadIdx.x;
    if (g < GN_G) cnt[g] = (float)(se[32 + g] - se[g]);
}

// Layer-1 gather. Gbf row 256 = [K64|QV128|S64]. 4 nodes/wave, 8-edge batch.
// Writes leaky(h1_pre) bf16 [N][64].
__global__ __launch_bounds__(256, 2) void edge_gather_w(
    const ushort* __restrict__ Gbf, ushort* __restrict__ Abf,
    const int* __restrict__ row_ptr, const int* __restrict__ elist)
{
    int w = threadIdx.x >> 6, c = threadIdx.x & 63;
    int n0 = blockIdx.x * 16 + w * 4;

    float k[4], acc[4];
    int beg[4], end[4];
    #pragma unroll
    for (int j = 0; j < 4; ++j) {
        int node = n0 + j;
        bool ok = node < GN_N;
        int nd = ok ? node : 0;
        beg[j] = row_ptr[nd];
        end[j] = ok ? row_ptr[nd + 1] : beg[j];
        k[j]   = bf2f(Gbf[(size_t)nd * 256 + c]);
        acc[j] = bf2f(Gbf[(size_t)nd * 256 + 192 + c]);
    }
    int s[32];
    #pragma unroll
    for (int j = 0; j < 4; ++j) {
        #pragma unroll
        for (int e = 0; e < 8; ++e) {
            int idx = beg[j] + e;
            s[j * 8 + e] = elist[idx < end[j] ? idx : 0];
        }
    }
    uint qv[32];
    #pragma unroll
    for (int je = 0; je < 32; ++je)
        qv[je] = *(const uint*)&Gbf[(size_t)s[je] * 256 + 64 + 2 * c];
    #pragma unroll
    for (int j = 0; j < 4; ++j) {
        #pragma unroll
        for (int e = 0; e < 8; ++e) {
            if (beg[j] + e < end[j]) {
                uint p = qv[j * 8 + e];
                float gt = k[j] + bf2f((ushort)(p & 0xffffu));
                if (gt > 0.f) acc[j] += gt * bf2f((ushort)(p >> 16));
            }
        }
    }
    #pragma unroll
    for (int j = 0; j < 4; ++j) {
        for (int i = beg[j] + 8; i < end[j]; ++i) {
            int ss = elist[i];
            uint p = *(const uint*)&Gbf[(size_t)ss * 256 + 64 + 2 * c];
            float gt = k[j] + bf2f((ushort)(p & 0xffffu));
            if (gt > 0.f) acc[j] += gt * bf2f((ushort)(p >> 16));
        }
    }
    #pragma unroll
    for (int j = 0; j < 4; ++j)
        if (n0 + j < GN_N) {
            float a = acc[j];
            a = a > 0.f ? a : 0.01f * a;   // leaky here (fp32) -> gemm is pure copy
            Abf[(size_t)(n0 + j) * 64 + c] = f2bf_rne(a);
        }
}

// Layer-2 dual gather. Gbf row 512 = [K128|QV256|S128]; thread handles
// channels c and 64+c. Writes leaky(h2_pre) bf16 [N][128].
__global__ __launch_bounds__(256, 2) void edge_gather_w2(
    const ushort* __restrict__ Gbf, ushort* __restrict__ Abf,
    const int* __restrict__ row_ptr, const int* __restrict__ elist)
{
    int w = threadIdx.x >> 6, c = threadIdx.x & 63;
    int n0 = blockIdx.x * 16 + w * 4;

    float k0[4], k1[4], a0[4], a1[4];
    int beg[4], end[4];
    #pragma unroll
    for (int j = 0; j < 4; ++j) {
        int node = n0 + j;
        bool ok = node < GN_N;
        int nd = ok ? node : 0;
        beg[j] = row_ptr[nd];
        end[j] = ok ? row_ptr[nd + 1] : beg[j];
        size_t b = (size_t)nd * 512;
        k0[j] = bf2f(Gbf[b + c]);
        k1[j] = bf2f(Gbf[b + 64 + c]);
        a0[j] = bf2f(Gbf[b + 384 + c]);
        a1[j] = bf2f(Gbf[b + 448 + c]);
    }
    int s[32];
    #pragma unroll
    for (int j = 0; j < 4; ++j) {
        #pragma unroll
        for (int e = 0; e < 8; ++e) {
            int idx = beg[j] + e;
            s[j * 8 + e] = elist[idx < end[j] ? idx : 0];
        }
    }
    uint qv0[32], qv1[32];
    #pragma unroll
    for (int je = 0; je < 32; ++je) {
        size_t b = (size_t)s[je] * 512;
        qv0[je] = *(const uint*)&Gbf[b + 128 + 2 * c];
        qv1[je] = *(const uint*)&Gbf[b + 256 + 2 * c];
    }
    #pragma unroll
    for (int j = 0; j < 4; ++j) {
        #pragma unroll
        for (int e = 0; e < 8; ++e) {
            if (beg[j] + e < end[j]) {
                uint p = qv0[j * 8 + e];
                float gt = k0[j] + bf2f((ushort)(p & 0xffffu));
                if (gt > 0.f) a0[j] += gt * bf2f((ushort)(p >> 16));
                uint q = qv1[j * 8 + e];
                float gu = k1[j] + bf2f((ushort)(q & 0xffffu));
                if (gu > 0.f) a1[j] += gu * bf2f((ushort)(q >> 16));
            }
        }
    }
    #pragma unroll
    for (int j = 0; j < 4; ++j) {
        for (int i = beg[j] + 8; i < end[j]; ++i) {
            size_t b = (size_t)elist[i] * 512;
            uint p = *(const uint*)&Gbf[b + 128 + 2 * c];
            uint q = *(const uint*)&Gbf[b + 256 + 2 * c];
            float gt = k0[j] + bf2f((ushort)(p & 0xffffu));
            if (gt > 0.f) a0[j] += gt * bf2f((ushort)(p >> 16));
            float gu = k1[j] + bf2f((ushort)(q & 0xffffu));
            if (gu > 0.f) a1[j] += gu * bf2f((ushort)(q >> 16));
        }
    }
    #pragma unroll
    for (int j = 0; j < 4; ++j)
        if (n0 + j < GN_N) {
            float x = a0[j], y = a1[j];
            x = x > 0.f ? x : 0.01f * x;
            y = y > 0.f ? y : 0.01f * y;
            Abf[(size_t)(n0 + j) * 128 + c]      = f2bf_rne(x);
            Abf[(size_t)(n0 + j) * 128 + 64 + c] = f2bf_rne(y);
        }
}

// Layer-3 dual gather + leaky + pool. Gbf row 512; channels c0+c, c0+64+c.
__global__ __launch_bounds__(256, 2) void edge_gather_pool2(
    const ushort* __restrict__ Gbf,
    const int* __restrict__ row_ptr, const int* __restrict__ elist,
    const int* __restrict__ batch,
    float* __restrict__ sums, int c0)
{
    __shared__ float red[16][128];
    __shared__ int gid[16];
    int w = threadIdx.x >> 6, c = threadIdx.x & 63;
    int n0 = blockIdx.x * 16 + w * 4;

    float k0[4], k1[4], a0[4], a1[4];
    int beg[4], end[4];
    #pragma unroll
    for (int j = 0; j < 4; ++j) {
        int node = n0 + j;
        bool ok = node < GN_N;
        int nd = ok ? node : 0;
        beg[j] = row_ptr[nd];
        end[j] = ok ? row_ptr[nd + 1] : beg[j];
        size_t b = (size_t)nd * 512;
        k0[j] = bf2f(Gbf[b + c]);
        k1[j] = bf2f(Gbf[b + 64 + c]);
        a0[j] = ok ? bf2f(Gbf[b + 384 + c]) : 0.f;
        a1[j] = ok ? bf2f(Gbf[b + 448 + c]) : 0.f;
    }
    int s[32];
    #pragma unroll
    for (int j = 0; j < 4; ++j) {
        #pragma unroll
        for (int e = 0; e < 8; ++e) {
            int idx = beg[j] + e;
            s[j * 8 + e] = elist[idx < end[j] ? idx : 0];
        }
    }
    uint qv0[32], qv1[32];
    #pragma unroll
    for (int je = 0; je < 32; ++je) {
        size_t b = (size_t)s[je] * 512;
        qv0[je] = *(const uint*)&Gbf[b + 128 + 2 * c];
        qv1[je] = *(const uint*)&Gbf[b + 256 + 2 * c];
    }
    #pragma unroll
    for (int j = 0; j < 4; ++j) {
        #pragma unroll
        for (int e = 0; e < 8; ++e) {
            if (beg[j] + e < end[j]) {
                uint p = qv0[j * 8 + e];
                float gt = k0[j] + bf2f((ushort)(p & 0xffffu));
                if (gt > 0.f) a0[j] += gt * bf2f((ushort)(p >> 16));
                uint q = qv1[j * 8 + e];
                float gu = k1[j] + bf2f((ushort)(q & 0xffffu));
                if (gu > 0.f) a1[j] += gu * bf2f((ushort)(q >> 16));
            }
        }
    }
    #pragma unroll
    for (int j = 0; j < 4; ++j) {
        for (int i = beg[j] + 8; i < end[j]; ++i) {
            size_t b = (size_t)elist[i] * 512;
            uint p = *(const uint*)&Gbf[b + 128 + 2 * c];
            uint q = *(const uint*)&Gbf[b + 256 + 2 * c];
            float gt = k0[j] + bf2f((ushort)(p & 0xffffu));
            if (gt > 0.f) a0[j] += gt * bf2f((ushort)(p >> 16));
            float gu = k1[j] + bf2f((ushort)(q & 0xffffu));
            if (gu > 0.f) a1[j] += gu * bf2f((ushort)(q >> 16));
        }
    }
    #pragma unroll
    for (int j = 0; j < 4; ++j) {
        float x = a0[j], y = a1[j];
        red[w * 4 + j][c]      = x > 0.f ? x : 0.01f * x;
        red[w * 4 + j][64 + c] = y > 0.f ? y : 0.01f * y;
    }
    if (c < 4) {
        int node = n0 + c;
        gid[w * 4 + c] = (node < GN_N) ? batch[node] : -1;
    }
    __syncthreads();
    if (w == 0) {
        int stripe = blockIdx.x & 31;
        int i = 0;
        while (i < 16) {
            int gg = gid[i];
            float s0 = 0.f, s1 = 0.f;
            int j = i;
            while (j < 16 && gid[j] == gg) { s0 += red[j][c]; s1 += red[j][64 + c]; ++j; }
            if (gg >= 0) {
                float* dstp = &sums[(size_t)(stripe * GN_G + gg) * 256 + c0 + c];
                atomicAdd(dstp, s0);
                atomicAdd(dstp + 64, s1);
            }
            i = j;
        }
    }
}

// One block per graph: reduce 32 stripes; Pl = sums[g]/cnt[g];
// Pg = Pl @ Wl3 + bl3; BN-MLP chain.
__global__ __launch_bounds__(256) void mlp_kernel(
    const float* __restrict__ sums, const float* __restrict__ cnt,
    const float* __restrict__ Wl3, const float* __restrict__ bl3,
    const float* __restrict__ W1, const float* __restrict__ b1,
    const float* __restrict__ Wh, const float* __restrict__ bh,
    const float* __restrict__ Wo, const float* __restrict__ bo,
    const float* __restrict__ gamma, const float* __restrict__ beta,
    const float* __restrict__ mean, const float* __restrict__ var,
    float* __restrict__ out)
{
    __shared__ float sp[256];
    __shared__ float pg[256];
    __shared__ float h0[64], h1[64];
    const int g = blockIdx.x;
    const int t = threadIdx.x;
    const float inv = 1.0f / fmaxf(cnt[g], 1.0f);

    {
        float acc = 0.f;
        #pragma unroll 8
        for (int st = 0; st < 32; ++st)
            acc += sums[(size_t)(st * GN_G + g) * 256 + t];
        sp[t] = acc * inv;
    }
    __syncthreads();

    {
        float a0 = 0.f, a1 = 0.f, a2 = 0.f, a3 = 0.f;
        #pragma unroll 4
        for (int k = 0; k < 256; k += 4) {
            a0 += sp[k + 0] * Wl3[(k + 0) * 256 + t];
            a1 += sp[k + 1] * Wl3[(k + 1) * 256 + t];
            a2 += sp[k + 2] * Wl3[(k + 2) * 256 + t];
            a3 += sp[k + 3] * Wl3[(k + 3) * 256 + t];
        }
        pg[t] = bl3[t] + ((a0 + a1) + (a2 + a3));
    }
    __syncthreads();

    if (t < 64) {
        float a0 = 0.f, a1 = 0.f, a2 = 0.f, a3 = 0.f;
        #pragma unroll 4
        for (int k = 0; k < 256; k += 4) {
            a0 += pg[k + 0] * W1[(k + 0) * 64 + t];
            a1 += pg[k + 1] * W1[(k + 1) * 64 + t];
            a2 += pg[k + 2] * W1[(k + 2) * 64 + t];
            a3 += pg[k + 3] * W1[(k + 3) * 64 + t];
        }
        float acc = b1[t] + ((a0 + a1) + (a2 + a3));
        float sc = gamma[t] * rsqrtf(var[t] + 1e-5f);
        acc = (acc - mean[t]) * sc + beta[t];
        h0[t] = fmaxf(acc, 0.0f);
    }
    __syncthreads();

    for (int L = 0; L < 3; ++L) {
        const float* W  = Wh + L * 64 * 64;
        const float* hin  = (L & 1) ? h1 : h0;
        float*       hout = (L & 1) ? h0 : h1;
        if (t < 64) {
            const float* ga = gamma + (L + 1) * 64;
            const float* be = beta  + (L + 1) * 64;
            const float* me = mean  + (L + 1) * 64;
            const float* va = var   + (L + 1) * 64;
            float a0 = 0.f, a1 = 0.f, a2 = 0.f, a3 = 0.f;
            #pragma unroll 4
            for (int k = 0; k < 64; k += 4) {
                a0 += hin[k + 0] * W[(k + 0) * 64 + t];
                a1 += hin[k + 1] * W[(k + 1) * 64 + t];
                a2 += hin[k + 2] * W[(k + 2) * 64 + t];
                a3 += hin[k + 3] * W[(k + 3) * 64 + t];
            }
            float acc = (bh + L * 64)[t] + ((a0 + a1) + (a2 + a3));
            float sc = ga[t] * rsqrtf(va[t] + 1e-5f);
            acc = (acc - me[t]) * sc + be[t];
            hout[t] = fmaxf(acc, 0.0f);
        }
        __syncthreads();
    }

    if (t < 8) {
        const float* hf = h1;
        float acc = bo[t];
        for (int k = 0; k < 64; ++k) acc += hf[k] * Wo[k * 8 + t];
        out[g * 8 + t] = acc;
    }
}

extern "C" void kernel_launch(void* const* d_in, const int* in_sizes, int n_in,
                              void* d_out, int out_size, void* d_ws, size_t ws_size,
                              hipStream_t stream)
{
    const int N = GN_N, E = GN_E;
    const float* x          = (const float*)d_in[0];
    const int*   edge_index = (const int*)d_in[1];
    const int*   batch      = (const int*)d_in[2];
    const int*   src = edge_index;
    const int*   dst = edge_index + E;
    auto F = [&](int i) { return (const float*)d_in[i]; };

    // ---- workspace layout ----
    float* ws    = (float*)d_ws;
    float* sums  = ws;                          // 32 stripes x 32 x 256
    float* cnt   = sums + 32 * GN_G * 256;      // 32
    float* bcat  = cnt + GN_G;                  // 1792
    ushort* Whi  = (ushort*)(bcat + 1792);
    ushort* Wlo  = Whi + W_TOTAL;
    ushort* xbf  = Wlo + W_TOTAL;               // N x 128 bf16
    ushort* h1bf = xbf + (size_t)N * 128;       // N x 64 bf16 (leaky'd)
    ushort* h2bf = h1bf + (size_t)N * 64;       // N x 128 bf16 (leaky'd)
    ushort* Gbf  = h2bf + (size_t)N * 128;      // N x 512 bf16
    int* deg     = (int*)(Gbf + (size_t)N * 512);
    int* cursor  = deg + N;
    int* row_ptr = cursor + N;                  // N+1
    int* elist   = row_ptr + (N + 1);           // E
    int* bsums   = elist + E;                   // 512
    int* se      = bsums + 512;                 // 64

    size_t need = (size_t)((char*)(se + 64) - (char*)ws);
    if (ws_size < need) return;

    // ---- CSR build + graph bounds ----
    const int eb = (E + 255) / 256;
    const int nb = (N + 255) / 256;
    zero_int<<<nb, 256, 0, stream>>>(deg, N);
    zero_int<<<1, 256, 0, stream>>>(se, 64);
    hist_kernel<<<eb, 256, 0, stream>>>(dst, deg);
    scan1<<<nb, 256, 0, stream>>>(deg, row_ptr, bsums);
    scan2<<<1, 512, 0, stream>>>(bsums, nb);
    scan3<<<nb, 256, 0, stream>>>(bsums, row_ptr, cursor);
    scatter_kernel<<<eb, 256, 0, stream>>>(src, dst, cursor, elist);
    bounds_kernel<<<nb, 256, 0, stream>>>(batch, se);
    cnt_kernel<<<1, 64, 0, stream>>>(se, cnt);

    // ---- weight prep: L1 pack; L2/L3 composed with previous Wl ----
    W1Src S1;
    for (int g = 0; g < 4; ++g) { S1.Wg[g] = F(3 + g); S1.bg[g] = F(7 + g); }
    wconv_l1<<<(32768 + 256 + 255) / 256, 256, 0, stream>>>(S1, Whi, Wlo, bcat);

    CSrc S2;
    S2.Wl = F(11); S2.bl = F(12);
    for (int g = 0; g < 4; ++g) { S2.Wg[g] = F(13 + g); S2.bg[g] = F(17 + g); }
    compose_l2<<<(512 * 64 + 255) / 256, 256, 0, stream>>>(S2, Whi, Wlo, bcat);

    CSrc S3;
    S3.Wl = F(21); S3.bl = F(22);
    for (int g = 0; g < 4; ++g) { S3.Wg[g] = F(23 + g); S3.bg[g] = F(27 + g); }
    compose_l3<<<(1024 * 128 + 255) / 256, 256, 0, stream>>>(S3, Whi, Wlo, bcat);

    aconv<<<(N * 16 + 255) / 256, 256, 0, stream>>>(x, xbf, sums);

    const int rb = (N + 127) / 128;
    const int gatherBlocks = (N + 15) / 16;

    // ---- layer 1 (256 cols: [K64|QV128|S64]) ----
    gemm2<<<dim3(2, rb), 512, 0, stream>>>(
        xbf, 128, Whi, Wlo, bcat, Gbf, 256, 128);
    edge_gather_w<<<gatherBlocks, 256, 0, stream>>>(Gbf, h1bf, row_ptr, elist);

    // ---- layer 2 (composed: leaky'd h1 @ Wl1Wg2; 512 cols, K=64) ----
    gemm2<<<dim3(4, rb), 512, 0, stream>>>(
        h1bf, 64, Whi + WOFF_L2, Wlo + WOFF_L2, bcat + 256, Gbf, 512, 64);
    edge_gather_w2<<<gatherBlocks, 256, 0, stream>>>(Gbf, h2bf, row_ptr, elist);

    // ---- layer 3 (composed: leaky'd h2 @ Wl2Wg3; 2 groups x 512, K=128) ----
    for (int ch = 0; ch < 2; ++ch) {
        size_t go = WOFF_L3 + (size_t)ch * 65536;
        gemm2<<<dim3(4, rb), 512, 0, stream>>>(
            h2bf, 128, Whi + go, Wlo + go, bcat + 768 + ch * 512, Gbf, 512, 128);
        edge_gather_pool2<<<gatherBlocks, 256, 0, stream>>>(
            Gbf, row_ptr, elist, batch, sums, ch * 128);
    }

    mlp_kernel<<<GN_G, 256, 0, stream>>>(sums, cnt, F(31), F(32),
                                         F(33), F(34), F(35), F(36), F(37), F(38),
                                         F(39), F(40), F(41), F(42),
                                         (float*)d_out);
}